// Round 1
// baseline (2882.242 us; speedup 1.0000x reference)
//
#include <hip/hip_runtime.h>
#include <math.h>

#define N_NODES   100000
#define N_EDGES   400000
#define N_INC     1600000
#define N_GRAPHS  512
#define ATOM_DIM  92
#define NODE_DIM  64
#define H_DIM     128
#define NUM_LAYERS 3
#define BN_EPS    1e-5f

__device__ __forceinline__ float softplus_f(float x) {
    // matches jax.nn.softplus = log1p(exp(x)), numerically stable
    return fmaxf(x, 0.f) + log1pf(expf(-fabsf(x)));
}

// h[n][f] = sum_k x[n][k] * W[k][f] + b[f]   (k < 92, f < 64)
__global__ void embed_kernel(const float* __restrict__ x, const float* __restrict__ W,
                             const float* __restrict__ b, float* __restrict__ h) {
    __shared__ float xs[4][ATOM_DIM];
    int node0 = blockIdx.x * 4;
    int tid = threadIdx.x;
    for (int i = tid; i < 4 * ATOM_DIM; i += 256) {
        int nn = i / ATOM_DIM, kk = i - nn * ATOM_DIM;
        int n = node0 + nn;
        xs[nn][kk] = (n < N_NODES) ? x[(size_t)n * ATOM_DIM + kk] : 0.f;
    }
    __syncthreads();
    int nn = tid >> 6, f = tid & 63;
    int n = node0 + nn;
    if (n >= N_NODES) return;
    float acc = b[f];
    #pragma unroll
    for (int k = 0; k < ATOM_DIM; ++k)
        acc = fmaf(xs[nn][k], W[k * NODE_DIM + f], acc);
    h[(size_t)n * NODE_DIM + f] = acc;
}

// hlin[n][f] = sum_k h[n][k] * W[k][f] + b[f]   (64x64)
__global__ void lin_kernel(const float* __restrict__ h, const float* __restrict__ W,
                           const float* __restrict__ b, float* __restrict__ hlin) {
    __shared__ float hs[4][NODE_DIM];
    int node0 = blockIdx.x * 4;
    int tid = threadIdx.x;
    {
        int nn = tid >> 6, k = tid & 63;
        int n = node0 + nn;
        hs[nn][k] = (n < N_NODES) ? h[(size_t)n * NODE_DIM + k] : 0.f;
    }
    __syncthreads();
    int nn = tid >> 6, f = tid & 63;
    int n = node0 + nn;
    if (n >= N_NODES) return;
    float acc = b[f];
    #pragma unroll
    for (int k = 0; k < NODE_DIM; ++k)
        acc = fmaf(hs[nn][k], W[k * NODE_DIM + f], acc);
    hlin[(size_t)n * NODE_DIM + f] = acc;
}

// degree counts (float) for nodes and edges
__global__ void deg_kernel(const int* __restrict__ ni, const int* __restrict__ ei,
                           float* __restrict__ dn, float* __restrict__ de) {
    int i = blockIdx.x * 256 + threadIdx.x;
    if (i >= N_INC) return;
    atomicAdd(&de[ei[i]], 1.f);
    atomicAdd(&dn[ni[i]], 1.f);
}

__global__ void inv_kernel(float* __restrict__ v, int n) {
    int i = blockIdx.x * 256 + threadIdx.x;
    if (i < n) {
        float d = v[i];
        v[i] = (d > 0.f) ? 1.f / d : 0.f;
    }
}

// node -> edge scatter: e_feat[e][f] += hlin[n][f]
__global__ void scatter_ne(const int* __restrict__ ni, const int* __restrict__ ei,
                           const float* __restrict__ hlin, float* __restrict__ efeat) {
    int gid = blockIdx.x * 256 + threadIdx.x;   // over N_INC*64
    int i = gid >> 6, f = gid & 63;
    if (i >= N_INC) return;
    int n = ni[i], e = ei[i];
    atomicAdd(&efeat[(size_t)e * 64 + f], hlin[(size_t)n * 64 + f]);
}

// edge -> node scatter: outr[n][f] += e_feat[e][f] * Binv[e]
__global__ void scatter_en(const int* __restrict__ ni, const int* __restrict__ ei,
                           const float* __restrict__ efeat, const float* __restrict__ binv,
                           float* __restrict__ outr) {
    int gid = blockIdx.x * 256 + threadIdx.x;   // over N_INC*64
    int i = gid >> 6, f = gid & 63;
    if (i >= N_INC) return;
    int n = ni[i], e = ei[i];
    float v = efeat[(size_t)e * 64 + f] * binv[e];
    atomicAdd(&outr[(size_t)n * 64 + f], v);
}

// per-feature sum and sumsq of outr[n][f] * dinv[n]
__global__ void stats_kernel(const float* __restrict__ outr, const float* __restrict__ dinv,
                             float* __restrict__ stats) {
    __shared__ float ss[256];
    __shared__ float s2[256];
    int tid = threadIdx.x;
    int f = tid & 63, r = tid >> 6;
    float a = 0.f, b = 0.f;
    for (int n = blockIdx.x * 4 + r; n < N_NODES; n += gridDim.x * 4) {
        float v = outr[(size_t)n * 64 + f] * dinv[n];
        a += v;
        b += v * v;
    }
    ss[tid] = a; s2[tid] = b;
    __syncthreads();
    if (tid < 128) { ss[tid] += ss[tid + 128]; s2[tid] += s2[tid + 128]; }
    __syncthreads();
    if (tid < 64) {
        atomicAdd(&stats[f],      ss[tid] + ss[tid + 64]);
        atomicAdd(&stats[64 + f], s2[tid] + s2[tid + 64]);
    }
}

// scale/shift from stats (biased variance)
__global__ void bnfin_kernel(const float* __restrict__ stats, const float* __restrict__ gamma,
                             const float* __restrict__ beta, float* __restrict__ scsh) {
    int f = threadIdx.x;
    if (f >= 64) return;
    const float invN = 1.f / (float)N_NODES;
    float mean = stats[f] * invN;
    float var  = stats[64 + f] * invN - mean * mean;
    var = fmaxf(var, 0.f);
    float sc = gamma[f] * rsqrtf(var + BN_EPS);
    scsh[f]      = sc;
    scsh[64 + f] = beta[f] - mean * sc;
}

// h[n][f] = softplus( (outr[n][f]*dinv[n]) * scale[f] + shift[f] )
__global__ void apply_kernel(const float* __restrict__ outr, const float* __restrict__ dinv,
                             const float* __restrict__ scsh, float* __restrict__ h) {
    int gid = blockIdx.x * 256 + threadIdx.x;   // over N_NODES*64
    int f = gid & 63, n = gid >> 6;
    if (n >= N_NODES) return;
    float v = outr[gid] * dinv[n];
    h[gid] = softplus_f(v * scsh[f] + scsh[64 + f]);
}

// scatter-mean pooling accumulation
__global__ void pool_kernel(const float* __restrict__ h, const int* __restrict__ batch,
                            float* __restrict__ pooled, float* __restrict__ cnt) {
    int gid = blockIdx.x * 256 + threadIdx.x;   // over N_NODES*64
    int f = gid & 63, n = gid >> 6;
    if (n >= N_NODES) return;
    int g = batch[n];
    atomicAdd(&pooled[(size_t)g * 64 + f], h[gid]);
    if (f == 0) atomicAdd(&cnt[g], 1.f);
}

// per-graph head: softplus(mean) -> fc(64->128)+softplus -> fco(128->1)
__global__ void head_kernel(const float* __restrict__ pooled, const float* __restrict__ cnt,
                            const float* __restrict__ fcW, const float* __restrict__ fcb,
                            const float* __restrict__ fcoW, const float* __restrict__ fcob,
                            float* __restrict__ out) {
    __shared__ float p[64];
    __shared__ float red[128];
    int g = blockIdx.x, tid = threadIdx.x;   // 128 threads
    if (tid < 64) {
        float c = fmaxf(cnt[g], 1.f);
        p[tid] = softplus_f(pooled[(size_t)g * 64 + tid] / c);
    }
    __syncthreads();
    float acc = fcb[tid];
    #pragma unroll
    for (int k = 0; k < 64; ++k)
        acc = fmaf(p[k], fcW[k * H_DIM + tid], acc);
    float h1 = softplus_f(acc);
    red[tid] = h1 * fcoW[tid];
    __syncthreads();
    for (int s = 64; s > 0; s >>= 1) {
        if (tid < s) red[tid] += red[tid + s];
        __syncthreads();
    }
    if (tid == 0) out[g] = red[0] + fcob[0];
}

extern "C" void kernel_launch(void* const* d_in, const int* in_sizes, int n_in,
                              void* d_out, int out_size, void* d_ws, size_t ws_size,
                              hipStream_t stream) {
    const float* x      = (const float*)d_in[0];
    const float* W_emb  = (const float*)d_in[1];
    const float* b_emb  = (const float*)d_in[2];
    const float* conv_W = (const float*)d_in[3];
    const float* conv_b = (const float*)d_in[4];
    const float* bn_g   = (const float*)d_in[5];
    const float* bn_b   = (const float*)d_in[6];
    const float* fc_W   = (const float*)d_in[7];
    const float* fc_b   = (const float*)d_in[8];
    const float* fco_W  = (const float*)d_in[9];
    const float* fco_b  = (const float*)d_in[10];
    const int* node_idx = (const int*)d_in[11];
    const int* edge_idx = (const int*)d_in[12];
    const int* batch    = (const int*)d_in[13];
    float* out = (float*)d_out;

    // workspace layout (floats)
    float* ws     = (float*)d_ws;
    float* h      = ws;                                   // 6,400,000
    float* hlin   = h     + (size_t)N_NODES * 64;         // 6,400,000
    float* outr   = hlin  + (size_t)N_NODES * 64;         // 6,400,000
    float* efeat  = outr  + (size_t)N_NODES * 64;         // 25,600,000
    float* binv   = efeat + (size_t)N_EDGES * 64;         // 400,000 (edge deg -> Binv)
    float* dinv   = binv  + N_EDGES;                      // 100,000 (node deg -> Dinv)
    float* stats  = dinv  + N_NODES;                      // 128 (sum | sumsq)
    float* scsh   = stats + 128;                          // 128 (scale | shift)
    float* pooled = scsh  + 128;                          // 32,768
    float* cnt    = pooled + (size_t)N_GRAPHS * 64;       // 512

    // --- degrees (once) + embedding ---
    hipMemsetAsync(binv, 0, (size_t)(N_EDGES + N_NODES) * sizeof(float), stream);
    embed_kernel<<<(N_NODES + 3) / 4, 256, 0, stream>>>(x, W_emb, b_emb, h);
    deg_kernel<<<(N_INC + 255) / 256, 256, 0, stream>>>(node_idx, edge_idx, dinv, binv);
    inv_kernel<<<(N_EDGES + N_NODES + 255) / 256, 256, 0, stream>>>(binv, N_EDGES + N_NODES);

    // --- 3 hypergraph conv layers ---
    for (int l = 0; l < NUM_LAYERS; ++l) {
        const float* Wl = conv_W + (size_t)l * NODE_DIM * NODE_DIM;
        const float* bl = conv_b + (size_t)l * NODE_DIM;

        lin_kernel<<<(N_NODES + 3) / 4, 256, 0, stream>>>(h, Wl, bl, hlin);

        hipMemsetAsync(efeat, 0, (size_t)N_EDGES * 64 * sizeof(float), stream);
        scatter_ne<<<(N_INC * 64) / 256, 256, 0, stream>>>(node_idx, edge_idx, hlin, efeat);

        hipMemsetAsync(outr, 0, (size_t)N_NODES * 64 * sizeof(float), stream);
        scatter_en<<<(N_INC * 64) / 256, 256, 0, stream>>>(node_idx, edge_idx, efeat, binv, outr);

        hipMemsetAsync(stats, 0, 128 * sizeof(float), stream);
        stats_kernel<<<1024, 256, 0, stream>>>(outr, dinv, stats);
        bnfin_kernel<<<1, 64, 0, stream>>>(stats, bn_g + (size_t)l * 64, bn_b + (size_t)l * 64, scsh);
        apply_kernel<<<(N_NODES * 64 + 255) / 256, 256, 0, stream>>>(outr, dinv, scsh, h);
    }

    // --- pooling + head ---
    hipMemsetAsync(pooled, 0, (size_t)(N_GRAPHS * 64 + N_GRAPHS) * sizeof(float), stream);
    pool_kernel<<<(N_NODES * 64 + 255) / 256, 256, 0, stream>>>(h, batch, pooled, cnt);
    head_kernel<<<N_GRAPHS, 128, 0, stream>>>(pooled, cnt, fc_W, fc_b, fco_W, fco_b, out);
}

// Round 2
// 2243.680 us; speedup vs baseline: 1.2846x; 1.2846x over previous
//
#include <hip/hip_runtime.h>
#include <math.h>

#define N_NODES   100000
#define N_EDGES   400000
#define N_INC     1600000
#define N_GRAPHS  512
#define ATOM_DIM  92
#define NODE_DIM  64
#define H_DIM     128
#define NUM_LAYERS 3
#define BN_EPS    1e-5f
#define SCAN_CHUNK 2048   // 256 threads * 8 elements

__device__ __forceinline__ float softplus_f(float x) {
    return fmaxf(x, 0.f) + log1pf(expf(-fabsf(x)));
}

// ---------------- dense little GEMMs ----------------

__global__ void embed_kernel(const float* __restrict__ x, const float* __restrict__ W,
                             const float* __restrict__ b, float* __restrict__ h) {
    __shared__ float xs[4][ATOM_DIM];
    int node0 = blockIdx.x * 4;
    int tid = threadIdx.x;
    for (int i = tid; i < 4 * ATOM_DIM; i += 256) {
        int nn = i / ATOM_DIM, kk = i - nn * ATOM_DIM;
        int n = node0 + nn;
        xs[nn][kk] = (n < N_NODES) ? x[(size_t)n * ATOM_DIM + kk] : 0.f;
    }
    __syncthreads();
    int nn = tid >> 6, f = tid & 63;
    int n = node0 + nn;
    if (n >= N_NODES) return;
    float acc = b[f];
    #pragma unroll
    for (int k = 0; k < ATOM_DIM; ++k)
        acc = fmaf(xs[nn][k], W[k * NODE_DIM + f], acc);
    h[(size_t)n * NODE_DIM + f] = acc;
}

__global__ void lin_kernel(const float* __restrict__ h, const float* __restrict__ W,
                           const float* __restrict__ b, float* __restrict__ hlin) {
    __shared__ float hs[4][NODE_DIM];
    int node0 = blockIdx.x * 4;
    int tid = threadIdx.x;
    {
        int nn = tid >> 6, k = tid & 63;
        int n = node0 + nn;
        hs[nn][k] = (n < N_NODES) ? h[(size_t)n * NODE_DIM + k] : 0.f;
    }
    __syncthreads();
    int nn = tid >> 6, f = tid & 63;
    int n = node0 + nn;
    if (n >= N_NODES) return;
    float acc = b[f];
    #pragma unroll
    for (int k = 0; k < NODE_DIM; ++k)
        acc = fmaf(hs[nn][k], W[k * NODE_DIM + f], acc);
    hlin[(size_t)n * NODE_DIM + f] = acc;
}

// ---------------- CSR build ----------------

__global__ void deg_kernel(const int* __restrict__ ni, const int* __restrict__ ei,
                           int* __restrict__ ncnt, int* __restrict__ ecnt) {
    int i = blockIdx.x * 256 + threadIdx.x;
    if (i >= N_INC) return;
    atomicAdd(&ecnt[ei[i]], 1);
    atomicAdd(&ncnt[ni[i]], 1);
}

__global__ void inv_from_cnt(const int* __restrict__ cnt, float* __restrict__ inv, int n) {
    int i = blockIdx.x * 256 + threadIdx.x;
    if (i < n) {
        int d = cnt[i];
        inv[i] = (d > 0) ? 1.f / (float)d : 0.f;
    }
}

// exclusive scan, 3-kernel: per-chunk scan, scan of chunk sums, add-back (+cursor copy)
__global__ void scan_block(const int* __restrict__ cnt, int n,
                           int* __restrict__ out, int* __restrict__ sums) {
    __shared__ int sh[256];
    int base = blockIdx.x * SCAN_CHUNK;
    int tid = threadIdx.x;
    int v[8];
    int local = 0;
    #pragma unroll
    for (int k = 0; k < 8; ++k) {
        int idx = base + tid * 8 + k;
        v[k] = (idx < n) ? cnt[idx] : 0;
        local += v[k];
    }
    sh[tid] = local;
    __syncthreads();
    for (int off = 1; off < 256; off <<= 1) {
        int t = (tid >= off) ? sh[tid - off] : 0;
        __syncthreads();
        sh[tid] += t;
        __syncthreads();
    }
    int run = sh[tid] - local;   // exclusive prefix of this thread
    if (tid == 255) sums[blockIdx.x] = sh[255];
    #pragma unroll
    for (int k = 0; k < 8; ++k) {
        int idx = base + tid * 8 + k;
        if (idx < n) out[idx] = run;
        run += v[k];
    }
}

__global__ void scan_sums(int* __restrict__ sums, int nsums) {
    __shared__ int sh[256];
    int tid = threadIdx.x;
    int v = (tid < nsums) ? sums[tid] : 0;
    sh[tid] = v;
    __syncthreads();
    for (int off = 1; off < 256; off <<= 1) {
        int t = (tid >= off) ? sh[tid - off] : 0;
        __syncthreads();
        sh[tid] += t;
        __syncthreads();
    }
    if (tid < nsums) {
        sums[tid] = sh[tid] - v;                 // exclusive
        if (tid == nsums - 1) sums[nsums] = sh[tid];  // grand total
    }
}

__global__ void scan_add(int* __restrict__ off, int n, const int* __restrict__ sums,
                         int* __restrict__ cursor) {
    int idx = blockIdx.x * 256 + threadIdx.x;
    if (idx < n) {
        int v = off[idx] + sums[idx / SCAN_CHUNK];
        off[idx] = v;
        cursor[idx] = v;
    } else if (idx == n) {
        off[n] = sums[(n + SCAN_CHUNK - 1) / SCAN_CHUNK];
    }
}

__global__ void csr_fill(const int* __restrict__ ni, const int* __restrict__ ei,
                         int* __restrict__ ecur, int* __restrict__ ncur,
                         int* __restrict__ elist, int* __restrict__ nlist) {
    int i = blockIdx.x * 256 + threadIdx.x;
    if (i >= N_INC) return;
    int n = ni[i], e = ei[i];
    int pe = atomicAdd(&ecur[e], 1);
    elist[pe] = n;
    int pn = atomicAdd(&ncur[n], 1);
    nlist[pn] = e;
}

// ---------------- gather aggregations ----------------

// efeat[e][f] = Binv[e] * sum_{n in e} hlin[n][f]      (one wave per edge)
__global__ void edge_agg(const int* __restrict__ eoff, const int* __restrict__ elist,
                         const float* __restrict__ hlin, const float* __restrict__ binv,
                         float* __restrict__ efeat) {
    int e = blockIdx.x * 4 + (threadIdx.x >> 6);
    int f = threadIdx.x & 63;
    if (e >= N_EDGES) return;
    int s = eoff[e], t = eoff[e + 1];
    float acc = 0.f;
    for (int j = s; j < t; ++j) {
        int n = elist[j];
        acc += hlin[(size_t)n * 64 + f];
    }
    efeat[(size_t)e * 64 + f] = acc * binv[e];
}

// outr[n][f] = Dinv[n] * sum_{e ∋ n} efeat[e][f]; fused per-feature sum/sumsq stats
__global__ void node_agg(const int* __restrict__ noff, const int* __restrict__ nlist,
                         const float* __restrict__ efeat, const float* __restrict__ dinv,
                         float* __restrict__ outr, float* __restrict__ stats) {
    __shared__ float ss[256];
    __shared__ float s2[256];
    int tid = threadIdx.x;
    int f = tid & 63, w = tid >> 6;
    float a = 0.f, b = 0.f;
    for (int n = blockIdx.x * 4 + w; n < N_NODES; n += gridDim.x * 4) {
        int s = noff[n], t = noff[n + 1];
        float acc = 0.f;
        for (int j = s; j < t; ++j) {
            int e = nlist[j];
            acc += efeat[(size_t)e * 64 + f];
        }
        float v = acc * dinv[n];
        outr[(size_t)n * 64 + f] = v;
        a += v;
        b += v * v;
    }
    ss[tid] = a; s2[tid] = b;
    __syncthreads();
    if (tid < 128) { ss[tid] += ss[tid + 128]; s2[tid] += s2[tid + 128]; }
    __syncthreads();
    if (tid < 64) {
        atomicAdd(&stats[f],      ss[tid] + ss[tid + 64]);
        atomicAdd(&stats[64 + f], s2[tid] + s2[tid + 64]);
    }
}

// ---------------- BN + softplus ----------------

__global__ void bnfin_kernel(const float* __restrict__ stats, const float* __restrict__ gamma,
                             const float* __restrict__ beta, float* __restrict__ scsh) {
    int f = threadIdx.x;
    if (f >= 64) return;
    const float invN = 1.f / (float)N_NODES;
    float mean = stats[f] * invN;
    float var  = stats[64 + f] * invN - mean * mean;
    var = fmaxf(var, 0.f);
    float sc = gamma[f] * rsqrtf(var + BN_EPS);
    scsh[f]      = sc;
    scsh[64 + f] = beta[f] - mean * sc;
}

__global__ void apply_kernel(const float* __restrict__ outr, const float* __restrict__ scsh,
                             float* __restrict__ h) {
    int gid = blockIdx.x * 256 + threadIdx.x;   // over N_NODES*64
    int f = gid & 63, n = gid >> 6;
    if (n >= N_NODES) return;
    float v = outr[gid];
    h[gid] = softplus_f(v * scsh[f] + scsh[64 + f]);
}

// ---------------- pooling + head ----------------

__global__ void pool_kernel(const float* __restrict__ h, const int* __restrict__ batch,
                            float* __restrict__ pooled, float* __restrict__ cnt) {
    int gid = blockIdx.x * 256 + threadIdx.x;   // over N_NODES*64
    int f = gid & 63, n = gid >> 6;
    if (n >= N_NODES) return;
    int g = batch[n];
    atomicAdd(&pooled[(size_t)g * 64 + f], h[gid]);
    if (f == 0) atomicAdd(&cnt[g], 1.f);
}

__global__ void head_kernel(const float* __restrict__ pooled, const float* __restrict__ cnt,
                            const float* __restrict__ fcW, const float* __restrict__ fcb,
                            const float* __restrict__ fcoW, const float* __restrict__ fcob,
                            float* __restrict__ out) {
    __shared__ float p[64];
    __shared__ float red[128];
    int g = blockIdx.x, tid = threadIdx.x;   // 128 threads
    if (tid < 64) {
        float c = fmaxf(cnt[g], 1.f);
        p[tid] = softplus_f(pooled[(size_t)g * 64 + tid] / c);
    }
    __syncthreads();
    float acc = fcb[tid];
    #pragma unroll
    for (int k = 0; k < 64; ++k)
        acc = fmaf(p[k], fcW[k * H_DIM + tid], acc);
    float h1 = softplus_f(acc);
    red[tid] = h1 * fcoW[tid];
    __syncthreads();
    for (int s = 64; s > 0; s >>= 1) {
        if (tid < s) red[tid] += red[tid + s];
        __syncthreads();
    }
    if (tid == 0) out[g] = red[0] + fcob[0];
}

// ---------------- launch ----------------

extern "C" void kernel_launch(void* const* d_in, const int* in_sizes, int n_in,
                              void* d_out, int out_size, void* d_ws, size_t ws_size,
                              hipStream_t stream) {
    const float* x      = (const float*)d_in[0];
    const float* W_emb  = (const float*)d_in[1];
    const float* b_emb  = (const float*)d_in[2];
    const float* conv_W = (const float*)d_in[3];
    const float* conv_b = (const float*)d_in[4];
    const float* bn_g   = (const float*)d_in[5];
    const float* bn_b   = (const float*)d_in[6];
    const float* fc_W   = (const float*)d_in[7];
    const float* fc_b   = (const float*)d_in[8];
    const float* fco_W  = (const float*)d_in[9];
    const float* fco_b  = (const float*)d_in[10];
    const int* node_idx = (const int*)d_in[11];
    const int* edge_idx = (const int*)d_in[12];
    const int* batch    = (const int*)d_in[13];
    float* out = (float*)d_out;

    // ---- workspace layout ----
    float* ws     = (float*)d_ws;
    float* h      = ws;                                   // 6.4M
    float* hlin   = h      + (size_t)N_NODES * 64;        // 6.4M
    float* outr   = hlin   + (size_t)N_NODES * 64;        // 6.4M
    float* efeat  = outr   + (size_t)N_NODES * 64;        // 25.6M
    float* binv   = efeat  + (size_t)N_EDGES * 64;        // 400K
    float* dinv   = binv   + N_EDGES;                     // 100K
    float* stats  = dinv   + N_NODES;                     // 128
    float* scsh   = stats  + 128;                         // 128
    float* pooled = scsh   + 128;                         // 32768
    float* cnt    = pooled + (size_t)N_GRAPHS * 64;       // 512
    int*   iws    = (int*)(cnt + N_GRAPHS);
    int*   ecnt   = iws;                                  // 400K (reused as edge cursor)
    int*   ncnt   = ecnt  + N_EDGES;                      // 100K (reused as node cursor)
    int*   eoff   = ncnt  + N_NODES;                      // 400K+1
    int*   noff   = eoff  + N_EDGES + 1;                  // 100K+1
    int*   esums  = noff  + N_NODES + 1;                  // 256
    int*   nsums  = esums + 256;                          // 256
    int*   elist  = nsums + 256;                          // 1.6M
    int*   nlist  = elist + N_INC;                        // 1.6M

    const int E_CHUNKS = (N_EDGES + SCAN_CHUNK - 1) / SCAN_CHUNK;  // 196
    const int N_CHUNKS = (N_NODES + SCAN_CHUNK - 1) / SCAN_CHUNK;  // 49

    // ---- CSR build + degrees ----
    hipMemsetAsync(ecnt, 0, (size_t)(N_EDGES + N_NODES) * sizeof(int), stream);
    deg_kernel<<<(N_INC + 255) / 256, 256, 0, stream>>>(node_idx, edge_idx, ncnt, ecnt);
    inv_from_cnt<<<(N_EDGES + 255) / 256, 256, 0, stream>>>(ecnt, binv, N_EDGES);
    inv_from_cnt<<<(N_NODES + 255) / 256, 256, 0, stream>>>(ncnt, dinv, N_NODES);
    scan_block<<<E_CHUNKS, 256, 0, stream>>>(ecnt, N_EDGES, eoff, esums);
    scan_sums<<<1, 256, 0, stream>>>(esums, E_CHUNKS);
    scan_add<<<(N_EDGES + 256) / 256, 256, 0, stream>>>(eoff, N_EDGES, esums, ecnt);
    scan_block<<<N_CHUNKS, 256, 0, stream>>>(ncnt, N_NODES, noff, nsums);
    scan_sums<<<1, 256, 0, stream>>>(nsums, N_CHUNKS);
    scan_add<<<(N_NODES + 256) / 256, 256, 0, stream>>>(noff, N_NODES, nsums, ncnt);
    csr_fill<<<(N_INC + 255) / 256, 256, 0, stream>>>(node_idx, edge_idx, ecnt, ncnt, elist, nlist);

    // ---- embedding ----
    embed_kernel<<<(N_NODES + 3) / 4, 256, 0, stream>>>(x, W_emb, b_emb, h);

    // ---- 3 hypergraph conv layers ----
    for (int l = 0; l < NUM_LAYERS; ++l) {
        const float* Wl = conv_W + (size_t)l * NODE_DIM * NODE_DIM;
        const float* bl = conv_b + (size_t)l * NODE_DIM;

        lin_kernel<<<(N_NODES + 3) / 4, 256, 0, stream>>>(h, Wl, bl, hlin);
        edge_agg<<<(N_EDGES + 3) / 4, 256, 0, stream>>>(eoff, elist, hlin, binv, efeat);
        hipMemsetAsync(stats, 0, 128 * sizeof(float), stream);
        node_agg<<<1024, 256, 0, stream>>>(noff, nlist, efeat, dinv, outr, stats);
        bnfin_kernel<<<1, 64, 0, stream>>>(stats, bn_g + (size_t)l * 64, bn_b + (size_t)l * 64, scsh);
        apply_kernel<<<(N_NODES * 64 + 255) / 256, 256, 0, stream>>>(outr, scsh, h);
    }

    // ---- pooling + head ----
    hipMemsetAsync(pooled, 0, (size_t)(N_GRAPHS * 64 + N_GRAPHS) * sizeof(float), stream);
    pool_kernel<<<(N_NODES * 64 + 255) / 256, 256, 0, stream>>>(h, batch, pooled, cnt);
    head_kernel<<<N_GRAPHS, 128, 0, stream>>>(pooled, cnt, fc_W, fc_b, fco_W, fco_b, out);
}

// Round 3
// 1526.145 us; speedup vs baseline: 1.8886x; 1.4702x over previous
//
#include <hip/hip_runtime.h>
#include <math.h>

#define N_NODES   100000
#define N_EDGES   400000
#define N_INC     1600000
#define N_GRAPHS  512
#define ATOM_DIM  92
#define NODE_DIM  64
#define H_DIM     128
#define NUM_LAYERS 3
#define BN_EPS    1e-5f
#define SCAN_CHUNK 2048   // 256 threads * 8 elements

__device__ __forceinline__ float softplus_f(float x) {
    return fmaxf(x, 0.f) + log1pf(expf(-fabsf(x)));
}

__device__ __forceinline__ float4 add4(float4 a, float4 b) {
    a.x += b.x; a.y += b.y; a.z += b.z; a.w += b.w; return a;
}
__device__ __forceinline__ float4 shflxor4(float4 v, int mask) {
    float4 r;
    r.x = __shfl_xor(v.x, mask); r.y = __shfl_xor(v.y, mask);
    r.z = __shfl_xor(v.z, mask); r.w = __shfl_xor(v.w, mask);
    return r;
}

// ---------------- embedding GEMM ----------------

__global__ void embed_kernel(const float* __restrict__ x, const float* __restrict__ W,
                             const float* __restrict__ b, float* __restrict__ h) {
    __shared__ float xs[4][ATOM_DIM];
    int node0 = blockIdx.x * 4;
    int tid = threadIdx.x;
    for (int i = tid; i < 4 * ATOM_DIM; i += 256) {
        int nn = i / ATOM_DIM, kk = i - nn * ATOM_DIM;
        int n = node0 + nn;
        xs[nn][kk] = (n < N_NODES) ? x[(size_t)n * ATOM_DIM + kk] : 0.f;
    }
    __syncthreads();
    int nn = tid >> 6, f = tid & 63;
    int n = node0 + nn;
    if (n >= N_NODES) return;
    float acc = b[f];
    #pragma unroll
    for (int k = 0; k < ATOM_DIM; ++k)
        acc = fmaf(xs[nn][k], W[k * NODE_DIM + f], acc);
    h[(size_t)n * NODE_DIM + f] = acc;
}

// ---------------- CSR build ----------------

__global__ void deg_kernel(const int* __restrict__ ni, const int* __restrict__ ei,
                           int* __restrict__ ncnt, int* __restrict__ ecnt) {
    int i = blockIdx.x * 256 + threadIdx.x;
    if (i >= N_INC) return;
    atomicAdd(&ecnt[ei[i]], 1);
    atomicAdd(&ncnt[ni[i]], 1);
}

__global__ void inv_from_cnt(const int* __restrict__ cnt, float* __restrict__ inv, int n) {
    int i = blockIdx.x * 256 + threadIdx.x;
    if (i < n) {
        int d = cnt[i];
        inv[i] = (d > 0) ? 1.f / (float)d : 0.f;
    }
}

__global__ void scan_block(const int* __restrict__ cnt, int n,
                           int* __restrict__ out, int* __restrict__ sums) {
    __shared__ int sh[256];
    int base = blockIdx.x * SCAN_CHUNK;
    int tid = threadIdx.x;
    int v[8];
    int local = 0;
    #pragma unroll
    for (int k = 0; k < 8; ++k) {
        int idx = base + tid * 8 + k;
        v[k] = (idx < n) ? cnt[idx] : 0;
        local += v[k];
    }
    sh[tid] = local;
    __syncthreads();
    for (int off = 1; off < 256; off <<= 1) {
        int t = (tid >= off) ? sh[tid - off] : 0;
        __syncthreads();
        sh[tid] += t;
        __syncthreads();
    }
    int run = sh[tid] - local;
    if (tid == 255) sums[blockIdx.x] = sh[255];
    #pragma unroll
    for (int k = 0; k < 8; ++k) {
        int idx = base + tid * 8 + k;
        if (idx < n) out[idx] = run;
        run += v[k];
    }
}

__global__ void scan_sums(int* __restrict__ sums, int nsums) {
    __shared__ int sh[256];
    int tid = threadIdx.x;
    int v = (tid < nsums) ? sums[tid] : 0;
    sh[tid] = v;
    __syncthreads();
    for (int off = 1; off < 256; off <<= 1) {
        int t = (tid >= off) ? sh[tid - off] : 0;
        __syncthreads();
        sh[tid] += t;
        __syncthreads();
    }
    if (tid < nsums) {
        sums[tid] = sh[tid] - v;
        if (tid == nsums - 1) sums[nsums] = sh[tid];
    }
}

__global__ void scan_add(int* __restrict__ off, int n, const int* __restrict__ sums,
                         int* __restrict__ cursor) {
    int idx = blockIdx.x * 256 + threadIdx.x;
    if (idx < n) {
        int v = off[idx] + sums[idx / SCAN_CHUNK];
        off[idx] = v;
        cursor[idx] = v;
    } else if (idx == n) {
        off[n] = sums[(n + SCAN_CHUNK - 1) / SCAN_CHUNK];
    }
}

__global__ void csr_fill(const int* __restrict__ ni, const int* __restrict__ ei,
                         int* __restrict__ ecur, int* __restrict__ ncur,
                         int* __restrict__ elist, int* __restrict__ nlist) {
    int i = blockIdx.x * 256 + threadIdx.x;
    if (i >= N_INC) return;
    int n = ni[i], e = ei[i];
    int pe = atomicAdd(&ecur[e], 1);
    elist[pe] = n;
    int pn = atomicAdd(&ncur[n], 1);
    nlist[pn] = e;
}

// ---------------- gather aggregations (float4, slot-parallel) ----------------

// efeat[e][:] = Binv[e] * sum_{n in e} h[n][:]   (one wave per edge)
__global__ void edge_agg(const int* __restrict__ eoff, const int* __restrict__ elist,
                         const float* __restrict__ h, const float* __restrict__ binv,
                         float4* __restrict__ efeat4) {
    int e = blockIdx.x * 4 + (threadIdx.x >> 6);
    if (e >= N_EDGES) return;
    int lane = threadIdx.x & 63;
    int m = lane >> 4, q = lane & 15;    // member slot, feature quad
    int s = eoff[e], t = eoff[e + 1];
    const float4* h4 = (const float4*)h;
    float4 acc = {0.f, 0.f, 0.f, 0.f};
    for (int j = s + m; j < t; j += 4) {
        int n = __ldg(&elist[j]);
        acc = add4(acc, h4[(size_t)n * 16 + q]);
    }
    acc = add4(acc, shflxor4(acc, 16));
    acc = add4(acc, shflxor4(acc, 32));
    if (m == 0) {
        float bv = binv[e];
        acc.x *= bv; acc.y *= bv; acc.z *= bv; acc.w *= bv;
        efeat4[(size_t)e * 16 + q] = acc;
    }
}

// out[n][:] = (Dinv[n] * sum_{e ∋ n} efeat[e][:]) @ W + b ; fused BN stats
__global__ void node_agg(const int* __restrict__ noff, const int* __restrict__ nlist,
                         const float4* __restrict__ efeat4, const float* __restrict__ dinv,
                         const float* __restrict__ W, const float* __restrict__ bvec,
                         float* __restrict__ outr, float* __restrict__ stats) {
    __shared__ float Ws[64 * 64];
    __shared__ float sA[4][64];
    __shared__ float sB[4][64];
    int tid = threadIdx.x;
    for (int i = tid; i < 64 * 64; i += 256) Ws[i] = W[i];
    __syncthreads();
    int wave = tid >> 6, lane = tid & 63;
    int slot = lane >> 4, q = lane & 15;
    float sa = 0.f, sb = 0.f;
    for (int n = blockIdx.x * 4 + wave; n < N_NODES; n += gridDim.x * 4) {
        int s = noff[n], t = noff[n + 1];
        float4 acc = {0.f, 0.f, 0.f, 0.f};
        for (int j = s + slot; j < t; j += 4) {
            int e = __ldg(&nlist[j]);
            acc = add4(acc, efeat4[(size_t)e * 16 + q]);
        }
        acc = add4(acc, shflxor4(acc, 16));
        acc = add4(acc, shflxor4(acc, 32));
        float dv = dinv[n];
        acc.x *= dv; acc.y *= dv; acc.z *= dv; acc.w *= dv;
        // per-wave GEMM: out[lane] = b[lane] + sum_k row[k] * Ws[k][lane]
        float out = bvec[lane];
        #pragma unroll
        for (int qq = 0; qq < 16; ++qq) {
            float4 av;
            av.x = __shfl(acc.x, qq); av.y = __shfl(acc.y, qq);
            av.z = __shfl(acc.z, qq); av.w = __shfl(acc.w, qq);
            out = fmaf(av.x, Ws[(4 * qq + 0) * 64 + lane], out);
            out = fmaf(av.y, Ws[(4 * qq + 1) * 64 + lane], out);
            out = fmaf(av.z, Ws[(4 * qq + 2) * 64 + lane], out);
            out = fmaf(av.w, Ws[(4 * qq + 3) * 64 + lane], out);
        }
        if (t == s) out = 0.f;   // isolated node: reference gives exactly 0
        outr[(size_t)n * 64 + lane] = out;
        sa += out; sb += out * out;
    }
    sA[wave][lane] = sa; sB[wave][lane] = sb;
    __syncthreads();
    if (tid < 64) {
        float a = sA[0][tid] + sA[1][tid] + sA[2][tid] + sA[3][tid];
        float b = sB[0][tid] + sB[1][tid] + sB[2][tid] + sB[3][tid];
        atomicAdd(&stats[tid], a);
        atomicAdd(&stats[64 + tid], b);
    }
}

// ---------------- BN + softplus ----------------

__global__ void bnfin_kernel(const float* __restrict__ stats, const float* __restrict__ gamma,
                             const float* __restrict__ beta, float* __restrict__ scsh) {
    int f = threadIdx.x;
    if (f >= 64) return;
    const float invN = 1.f / (float)N_NODES;
    float mean = stats[f] * invN;
    float var  = stats[64 + f] * invN - mean * mean;
    var = fmaxf(var, 0.f);
    float sc = gamma[f] * rsqrtf(var + BN_EPS);
    scsh[f]      = sc;
    scsh[64 + f] = beta[f] - mean * sc;
}

__global__ void apply_kernel(const float4* __restrict__ outr4, const float* __restrict__ scsh,
                             float4* __restrict__ h4) {
    int gid = blockIdx.x * 256 + threadIdx.x;   // over N_NODES*16 quads
    if (gid >= N_NODES * 16) return;
    int qq = gid & 15;
    float4 v  = outr4[gid];
    float4 sc = ((const float4*)scsh)[qq];
    float4 sh = ((const float4*)(scsh + 64))[qq];
    float4 r;
    r.x = softplus_f(fmaf(v.x, sc.x, sh.x));
    r.y = softplus_f(fmaf(v.y, sc.y, sh.y));
    r.z = softplus_f(fmaf(v.z, sc.z, sh.z));
    r.w = softplus_f(fmaf(v.w, sc.w, sh.w));
    h4[gid] = r;
}

// ---------------- pooling + head ----------------

__global__ void pool_kernel(const float* __restrict__ h, const int* __restrict__ batch,
                            float* __restrict__ pooled, float* __restrict__ cnt) {
    int gid = blockIdx.x * 256 + threadIdx.x;   // over N_NODES*64
    int f = gid & 63, n = gid >> 6;
    if (n >= N_NODES) return;
    int g = batch[n];
    atomicAdd(&pooled[(size_t)g * 64 + f], h[gid]);
    if (f == 0) atomicAdd(&cnt[g], 1.f);
}

__global__ void head_kernel(const float* __restrict__ pooled, const float* __restrict__ cnt,
                            const float* __restrict__ fcW, const float* __restrict__ fcb,
                            const float* __restrict__ fcoW, const float* __restrict__ fcob,
                            float* __restrict__ out) {
    __shared__ float p[64];
    __shared__ float red[128];
    int g = blockIdx.x, tid = threadIdx.x;   // 128 threads
    if (tid < 64) {
        float c = fmaxf(cnt[g], 1.f);
        p[tid] = softplus_f(pooled[(size_t)g * 64 + tid] / c);
    }
    __syncthreads();
    float acc = fcb[tid];
    #pragma unroll
    for (int k = 0; k < 64; ++k)
        acc = fmaf(p[k], fcW[k * H_DIM + tid], acc);
    float h1 = softplus_f(acc);
    red[tid] = h1 * fcoW[tid];
    __syncthreads();
    for (int s = 64; s > 0; s >>= 1) {
        if (tid < s) red[tid] += red[tid + s];
        __syncthreads();
    }
    if (tid == 0) out[g] = red[0] + fcob[0];
}

// ---------------- launch ----------------

extern "C" void kernel_launch(void* const* d_in, const int* in_sizes, int n_in,
                              void* d_out, int out_size, void* d_ws, size_t ws_size,
                              hipStream_t stream) {
    const float* x      = (const float*)d_in[0];
    const float* W_emb  = (const float*)d_in[1];
    const float* b_emb  = (const float*)d_in[2];
    const float* conv_W = (const float*)d_in[3];
    const float* conv_b = (const float*)d_in[4];
    const float* bn_g   = (const float*)d_in[5];
    const float* bn_b   = (const float*)d_in[6];
    const float* fc_W   = (const float*)d_in[7];
    const float* fc_b   = (const float*)d_in[8];
    const float* fco_W  = (const float*)d_in[9];
    const float* fco_b  = (const float*)d_in[10];
    const int* node_idx = (const int*)d_in[11];
    const int* edge_idx = (const int*)d_in[12];
    const int* batch    = (const int*)d_in[13];
    float* out = (float*)d_out;

    // ---- workspace layout ----
    float* ws     = (float*)d_ws;
    float* h      = ws;                                   // 6.4M
    float* outr   = h      + (size_t)N_NODES * 64;        // 6.4M
    float* efeat  = outr   + (size_t)N_NODES * 64;        // 25.6M
    float* binv   = efeat  + (size_t)N_EDGES * 64;        // 400K
    float* dinv   = binv   + N_EDGES;                     // 100K
    float* stats  = dinv   + N_NODES;                     // 128
    float* scsh   = stats  + 128;                         // 128
    float* pooled = scsh   + 128;                         // 32768
    float* cnt    = pooled + (size_t)N_GRAPHS * 64;       // 512
    int*   iws    = (int*)(cnt + N_GRAPHS);
    int*   ecnt   = iws;                                  // 400K (reused as cursor)
    int*   ncnt   = ecnt  + N_EDGES;                      // 100K (reused as cursor)
    int*   eoff   = ncnt  + N_NODES;                      // 400K+1
    int*   noff   = eoff  + N_EDGES + 1;                  // 100K+1
    int*   esums  = noff  + N_NODES + 1;                  // 256
    int*   nsums  = esums + 256;                          // 256
    int*   elist  = nsums + 256;                          // 1.6M
    int*   nlist  = elist + N_INC;                        // 1.6M

    const int E_CHUNKS = (N_EDGES + SCAN_CHUNK - 1) / SCAN_CHUNK;
    const int N_CHUNKS = (N_NODES + SCAN_CHUNK - 1) / SCAN_CHUNK;

    // ---- CSR build + degrees ----
    hipMemsetAsync(ecnt, 0, (size_t)(N_EDGES + N_NODES) * sizeof(int), stream);
    deg_kernel<<<(N_INC + 255) / 256, 256, 0, stream>>>(node_idx, edge_idx, ncnt, ecnt);
    inv_from_cnt<<<(N_EDGES + 255) / 256, 256, 0, stream>>>(ecnt, binv, N_EDGES);
    inv_from_cnt<<<(N_NODES + 255) / 256, 256, 0, stream>>>(ncnt, dinv, N_NODES);
    scan_block<<<E_CHUNKS, 256, 0, stream>>>(ecnt, N_EDGES, eoff, esums);
    scan_sums<<<1, 256, 0, stream>>>(esums, E_CHUNKS);
    scan_add<<<(N_EDGES + 256) / 256, 256, 0, stream>>>(eoff, N_EDGES, esums, ecnt);
    scan_block<<<N_CHUNKS, 256, 0, stream>>>(ncnt, N_NODES, noff, nsums);
    scan_sums<<<1, 256, 0, stream>>>(nsums, N_CHUNKS);
    scan_add<<<(N_NODES + 256) / 256, 256, 0, stream>>>(noff, N_NODES, nsums, ncnt);
    csr_fill<<<(N_INC + 255) / 256, 256, 0, stream>>>(node_idx, edge_idx, ecnt, ncnt, elist, nlist);

    // ---- embedding ----
    embed_kernel<<<(N_NODES + 3) / 4, 256, 0, stream>>>(x, W_emb, b_emb, h);

    // ---- 3 hypergraph conv layers: agg = P h; out = agg@W + b; BN; softplus ----
    for (int l = 0; l < NUM_LAYERS; ++l) {
        const float* Wl = conv_W + (size_t)l * NODE_DIM * NODE_DIM;
        const float* bl = conv_b + (size_t)l * NODE_DIM;

        edge_agg<<<(N_EDGES + 3) / 4, 256, 0, stream>>>(eoff, elist, h, binv, (float4*)efeat);
        hipMemsetAsync(stats, 0, 128 * sizeof(float), stream);
        node_agg<<<1024, 256, 0, stream>>>(noff, nlist, (const float4*)efeat, dinv,
                                           Wl, bl, outr, stats);
        bnfin_kernel<<<1, 64, 0, stream>>>(stats, bn_g + (size_t)l * 64, bn_b + (size_t)l * 64, scsh);
        apply_kernel<<<(N_NODES * 16 + 255) / 256, 256, 0, stream>>>((const float4*)outr, scsh, (float4*)h);
    }

    // ---- pooling + head ----
    hipMemsetAsync(pooled, 0, (size_t)(N_GRAPHS * 64 + N_GRAPHS) * sizeof(float), stream);
    pool_kernel<<<(N_NODES * 64 + 255) / 256, 256, 0, stream>>>(h, batch, pooled, cnt);
    head_kernel<<<N_GRAPHS, 128, 0, stream>>>(pooled, cnt, fc_W, fc_b, fco_W, fco_b, out);
}

// Round 4
// 1507.336 us; speedup vs baseline: 1.9121x; 1.0125x over previous
//
#include <hip/hip_runtime.h>
#include <hip/hip_fp16.h>
#include <math.h>

#define N_NODES   100000
#define N_EDGES   400000
#define N_INC     1600000
#define N_GRAPHS  512
#define ATOM_DIM  92
#define NODE_DIM  64
#define H_DIM     128
#define NUM_LAYERS 3
#define BN_EPS    1e-5f
#define SCAN_CHUNK 2048   // 256 threads * 8 elements

struct alignas(8) half4 { __half2 a, b; };

__device__ __forceinline__ float softplus_f(float x) {
    return fmaxf(x, 0.f) + log1pf(expf(-fabsf(x)));
}

__device__ __forceinline__ float4 add4(float4 a, float4 b) {
    a.x += b.x; a.y += b.y; a.z += b.z; a.w += b.w; return a;
}
__device__ __forceinline__ float4 shflxor4(float4 v, int mask) {
    float4 r;
    r.x = __shfl_xor(v.x, mask); r.y = __shfl_xor(v.y, mask);
    r.z = __shfl_xor(v.z, mask); r.w = __shfl_xor(v.w, mask);
    return r;
}

// ---------------- embedding GEMM (fp32 in, fp16 out) ----------------

__global__ void embed_kernel(const float* __restrict__ x, const float* __restrict__ W,
                             const float* __restrict__ b, __half* __restrict__ h16) {
    __shared__ float xs[4][ATOM_DIM];
    int node0 = blockIdx.x * 4;
    int tid = threadIdx.x;
    for (int i = tid; i < 4 * ATOM_DIM; i += 256) {
        int nn = i / ATOM_DIM, kk = i - nn * ATOM_DIM;
        int n = node0 + nn;
        xs[nn][kk] = (n < N_NODES) ? x[(size_t)n * ATOM_DIM + kk] : 0.f;
    }
    __syncthreads();
    int nn = tid >> 6, f = tid & 63;
    int n = node0 + nn;
    if (n >= N_NODES) return;
    float acc = b[f];
    #pragma unroll
    for (int k = 0; k < ATOM_DIM; ++k)
        acc = fmaf(xs[nn][k], W[k * NODE_DIM + f], acc);
    h16[(size_t)n * NODE_DIM + f] = __float2half_rn(acc);
}

// ---------------- CSR build ----------------

__global__ void deg_kernel(const int* __restrict__ ni, const int* __restrict__ ei,
                           int* __restrict__ ncnt, int* __restrict__ ecnt) {
    int i = blockIdx.x * 256 + threadIdx.x;
    if (i >= N_INC) return;
    atomicAdd(&ecnt[ei[i]], 1);
    atomicAdd(&ncnt[ni[i]], 1);
}

__global__ void inv_from_cnt(const int* __restrict__ cnt, float* __restrict__ inv, int n) {
    int i = blockIdx.x * 256 + threadIdx.x;
    if (i < n) {
        int d = cnt[i];
        inv[i] = (d > 0) ? 1.f / (float)d : 0.f;
    }
}

__global__ void scan_block(const int* __restrict__ cnt, int n,
                           int* __restrict__ out, int* __restrict__ sums) {
    __shared__ int sh[256];
    int base = blockIdx.x * SCAN_CHUNK;
    int tid = threadIdx.x;
    int v[8];
    int local = 0;
    #pragma unroll
    for (int k = 0; k < 8; ++k) {
        int idx = base + tid * 8 + k;
        v[k] = (idx < n) ? cnt[idx] : 0;
        local += v[k];
    }
    sh[tid] = local;
    __syncthreads();
    for (int off = 1; off < 256; off <<= 1) {
        int t = (tid >= off) ? sh[tid - off] : 0;
        __syncthreads();
        sh[tid] += t;
        __syncthreads();
    }
    int run = sh[tid] - local;
    if (tid == 255) sums[blockIdx.x] = sh[255];
    #pragma unroll
    for (int k = 0; k < 8; ++k) {
        int idx = base + tid * 8 + k;
        if (idx < n) out[idx] = run;
        run += v[k];
    }
}

__global__ void scan_sums(int* __restrict__ sums, int nsums) {
    __shared__ int sh[256];
    int tid = threadIdx.x;
    int v = (tid < nsums) ? sums[tid] : 0;
    sh[tid] = v;
    __syncthreads();
    for (int off = 1; off < 256; off <<= 1) {
        int t = (tid >= off) ? sh[tid - off] : 0;
        __syncthreads();
        sh[tid] += t;
        __syncthreads();
    }
    if (tid < nsums) {
        sums[tid] = sh[tid] - v;
        if (tid == nsums - 1) sums[nsums] = sh[tid];
    }
}

__global__ void scan_add(int* __restrict__ off, int n, const int* __restrict__ sums,
                         int* __restrict__ cursor) {
    int idx = blockIdx.x * 256 + threadIdx.x;
    if (idx < n) {
        int v = off[idx] + sums[idx / SCAN_CHUNK];
        off[idx] = v;
        cursor[idx] = v;
    } else if (idx == n) {
        off[n] = sums[(n + SCAN_CHUNK - 1) / SCAN_CHUNK];
    }
}

__global__ void csr_fill(const int* __restrict__ ni, const int* __restrict__ ei,
                         int* __restrict__ ecur, int* __restrict__ ncur,
                         int* __restrict__ elist, int* __restrict__ nlist) {
    int i = blockIdx.x * 256 + threadIdx.x;
    if (i >= N_INC) return;
    int n = ni[i], e = ei[i];
    int pe = atomicAdd(&ecur[e], 1);
    elist[pe] = n;
    int pn = atomicAdd(&ncur[n], 1);
    nlist[pn] = e;
}

// ---------------- gather aggregations (fp16 storage, fp32 math) ----------------

// efeat[e][:] = Binv[e] * sum_{n in e} h[n][:]   (one wave per edge; 4 member slots x 16 quad lanes)
__global__ void edge_agg(const int* __restrict__ eoff, const int* __restrict__ elist,
                         const half4* __restrict__ h4, const float* __restrict__ binv,
                         half4* __restrict__ efeat4) {
    int e = blockIdx.x * 4 + (threadIdx.x >> 6);
    if (e >= N_EDGES) return;
    int lane = threadIdx.x & 63;
    int m = lane >> 4, q = lane & 15;    // member slot, feature quad
    int s = eoff[e], t = eoff[e + 1];
    float4 acc = {0.f, 0.f, 0.f, 0.f};
    for (int j = s + m; j < t; j += 4) {
        int n = __ldg(&elist[j]);
        half4 v = h4[(size_t)n * 16 + q];
        float2 lo = __half22float2(v.a), hi = __half22float2(v.b);
        acc.x += lo.x; acc.y += lo.y; acc.z += hi.x; acc.w += hi.y;
    }
    acc = add4(acc, shflxor4(acc, 16));
    acc = add4(acc, shflxor4(acc, 32));
    if (m == 0) {
        float bv = binv[e];
        half4 r;
        r.a = __floats2half2_rn(acc.x * bv, acc.y * bv);
        r.b = __floats2half2_rn(acc.z * bv, acc.w * bv);
        efeat4[(size_t)e * 16 + q] = r;
    }
}

// out[n][:] = (Dinv[n] * sum_{e ∋ n} efeat[e][:]) @ W + b ; fused BN stats; fp16 out
__global__ void node_agg(const int* __restrict__ noff, const int* __restrict__ nlist,
                         const half4* __restrict__ efeat4, const float* __restrict__ dinv,
                         const float* __restrict__ W, const float* __restrict__ bvec,
                         __half* __restrict__ outr16, float* __restrict__ stats) {
    __shared__ float Ws[64 * 64];
    __shared__ float sA[4][64];
    __shared__ float sB[4][64];
    int tid = threadIdx.x;
    for (int i = tid; i < 64 * 64; i += 256) Ws[i] = W[i];
    __syncthreads();
    int wave = tid >> 6, lane = tid & 63;
    int slot = lane >> 4, q = lane & 15;
    float sa = 0.f, sb = 0.f;
    for (int n = blockIdx.x * 4 + wave; n < N_NODES; n += gridDim.x * 4) {
        int s = noff[n], t = noff[n + 1];
        float4 acc = {0.f, 0.f, 0.f, 0.f};
        for (int j = s + slot; j < t; j += 4) {
            int e = __ldg(&nlist[j]);
            half4 v = efeat4[(size_t)e * 16 + q];
            float2 lo = __half22float2(v.a), hi = __half22float2(v.b);
            acc.x += lo.x; acc.y += lo.y; acc.z += hi.x; acc.w += hi.y;
        }
        acc = add4(acc, shflxor4(acc, 16));
        acc = add4(acc, shflxor4(acc, 32));
        float dv = dinv[n];
        acc.x *= dv; acc.y *= dv; acc.z *= dv; acc.w *= dv;
        // per-wave GEMM: out[lane] = b[lane] + sum_k row[k] * Ws[k][lane]
        float out = bvec[lane];
        #pragma unroll
        for (int qq = 0; qq < 16; ++qq) {
            float4 av;
            av.x = __shfl(acc.x, qq); av.y = __shfl(acc.y, qq);
            av.z = __shfl(acc.z, qq); av.w = __shfl(acc.w, qq);
            out = fmaf(av.x, Ws[(4 * qq + 0) * 64 + lane], out);
            out = fmaf(av.y, Ws[(4 * qq + 1) * 64 + lane], out);
            out = fmaf(av.z, Ws[(4 * qq + 2) * 64 + lane], out);
            out = fmaf(av.w, Ws[(4 * qq + 3) * 64 + lane], out);
        }
        if (t == s) out = 0.f;   // isolated node: reference gives exactly 0
        outr16[(size_t)n * 64 + lane] = __float2half_rn(out);
        sa += out; sb += out * out;
    }
    sA[wave][lane] = sa; sB[wave][lane] = sb;
    __syncthreads();
    if (tid < 64) {
        float a = sA[0][tid] + sA[1][tid] + sA[2][tid] + sA[3][tid];
        float b = sB[0][tid] + sB[1][tid] + sB[2][tid] + sB[3][tid];
        atomicAdd(&stats[tid], a);
        atomicAdd(&stats[64 + tid], b);
    }
}

// ---------------- BN + softplus ----------------

__global__ void bnfin_kernel(const float* __restrict__ stats, const float* __restrict__ gamma,
                             const float* __restrict__ beta, float* __restrict__ scsh) {
    int f = threadIdx.x;
    if (f >= 64) return;
    const float invN = 1.f / (float)N_NODES;
    float mean = stats[f] * invN;
    float var  = stats[64 + f] * invN - mean * mean;
    var = fmaxf(var, 0.f);
    float sc = gamma[f] * rsqrtf(var + BN_EPS);
    scsh[f]      = sc;
    scsh[64 + f] = beta[f] - mean * sc;
}

__global__ void apply_kernel(const half4* __restrict__ outr4, const float* __restrict__ scsh,
                             half4* __restrict__ h4) {
    int gid = blockIdx.x * 256 + threadIdx.x;   // over N_NODES*16 quads
    if (gid >= N_NODES * 16) return;
    int qq = gid & 15;
    half4 v = outr4[gid];
    float2 lo = __half22float2(v.a), hi = __half22float2(v.b);
    float4 sc = ((const float4*)scsh)[qq];
    float4 sh = ((const float4*)(scsh + 64))[qq];
    half4 r;
    r.a = __floats2half2_rn(softplus_f(fmaf(lo.x, sc.x, sh.x)),
                            softplus_f(fmaf(lo.y, sc.y, sh.y)));
    r.b = __floats2half2_rn(softplus_f(fmaf(hi.x, sc.z, sh.z)),
                            softplus_f(fmaf(hi.y, sc.w, sh.w)));
    h4[gid] = r;
}

// ---------------- pooling + head ----------------

__global__ void pool_kernel(const __half* __restrict__ h16, const int* __restrict__ batch,
                            float* __restrict__ pooled, float* __restrict__ cnt) {
    int gid = blockIdx.x * 256 + threadIdx.x;   // over N_NODES*64
    int f = gid & 63, n = gid >> 6;
    if (n >= N_NODES) return;
    int g = batch[n];
    atomicAdd(&pooled[(size_t)g * 64 + f], __half2float(h16[gid]));
    if (f == 0) atomicAdd(&cnt[g], 1.f);
}

__global__ void head_kernel(const float* __restrict__ pooled, const float* __restrict__ cnt,
                            const float* __restrict__ fcW, const float* __restrict__ fcb,
                            const float* __restrict__ fcoW, const float* __restrict__ fcob,
                            float* __restrict__ out) {
    __shared__ float p[64];
    __shared__ float red[128];
    int g = blockIdx.x, tid = threadIdx.x;   // 128 threads
    if (tid < 64) {
        float c = fmaxf(cnt[g], 1.f);
        p[tid] = softplus_f(pooled[(size_t)g * 64 + tid] / c);
    }
    __syncthreads();
    float acc = fcb[tid];
    #pragma unroll
    for (int k = 0; k < 64; ++k)
        acc = fmaf(p[k], fcW[k * H_DIM + tid], acc);
    float h1 = softplus_f(acc);
    red[tid] = h1 * fcoW[tid];
    __syncthreads();
    for (int s = 64; s > 0; s >>= 1) {
        if (tid < s) red[tid] += red[tid + s];
        __syncthreads();
    }
    if (tid == 0) out[g] = red[0] + fcob[0];
}

// ---------------- launch ----------------

extern "C" void kernel_launch(void* const* d_in, const int* in_sizes, int n_in,
                              void* d_out, int out_size, void* d_ws, size_t ws_size,
                              hipStream_t stream) {
    const float* x      = (const float*)d_in[0];
    const float* W_emb  = (const float*)d_in[1];
    const float* b_emb  = (const float*)d_in[2];
    const float* conv_W = (const float*)d_in[3];
    const float* conv_b = (const float*)d_in[4];
    const float* bn_g   = (const float*)d_in[5];
    const float* bn_b   = (const float*)d_in[6];
    const float* fc_W   = (const float*)d_in[7];
    const float* fc_b   = (const float*)d_in[8];
    const float* fco_W  = (const float*)d_in[9];
    const float* fco_b  = (const float*)d_in[10];
    const int* node_idx = (const int*)d_in[11];
    const int* edge_idx = (const int*)d_in[12];
    const int* batch    = (const int*)d_in[13];
    float* out = (float*)d_out;

    // ---- workspace layout (fp16 feature buffers first, 8B-aligned) ----
    __half* h16    = (__half*)d_ws;                        // 6.4M halves (12.8 MB)
    __half* outr16 = h16    + (size_t)N_NODES * 64;        // 6.4M halves
    __half* efeat16= outr16 + (size_t)N_NODES * 64;        // 25.6M halves (51.2 MB)
    float* binv    = (float*)(efeat16 + (size_t)N_EDGES * 64); // 400K
    float* dinv    = binv   + N_EDGES;                     // 100K
    float* stats   = dinv   + N_NODES;                     // 128
    float* scsh    = stats  + 128;                         // 128
    float* pooled  = scsh   + 128;                         // 32768
    float* cnt     = pooled + (size_t)N_GRAPHS * 64;       // 512
    int*   ecnt    = (int*)(cnt + N_GRAPHS);               // 400K (reused as cursor)
    int*   ncnt    = ecnt  + N_EDGES;                      // 100K (reused as cursor)
    int*   eoff    = ncnt  + N_NODES;                      // 400K+1
    int*   noff    = eoff  + N_EDGES + 1;                  // 100K+1
    int*   esums   = noff  + N_NODES + 1;                  // 256
    int*   nsums   = esums + 256;                          // 256
    int*   elist   = nsums + 256;                          // 1.6M
    int*   nlist   = elist + N_INC;                        // 1.6M

    const int E_CHUNKS = (N_EDGES + SCAN_CHUNK - 1) / SCAN_CHUNK;
    const int N_CHUNKS = (N_NODES + SCAN_CHUNK - 1) / SCAN_CHUNK;

    // ---- CSR build + degrees ----
    hipMemsetAsync(ecnt, 0, (size_t)(N_EDGES + N_NODES) * sizeof(int), stream);
    deg_kernel<<<(N_INC + 255) / 256, 256, 0, stream>>>(node_idx, edge_idx, ncnt, ecnt);
    inv_from_cnt<<<(N_EDGES + 255) / 256, 256, 0, stream>>>(ecnt, binv, N_EDGES);
    inv_from_cnt<<<(N_NODES + 255) / 256, 256, 0, stream>>>(ncnt, dinv, N_NODES);
    scan_block<<<E_CHUNKS, 256, 0, stream>>>(ecnt, N_EDGES, eoff, esums);
    scan_sums<<<1, 256, 0, stream>>>(esums, E_CHUNKS);
    scan_add<<<(N_EDGES + 256) / 256, 256, 0, stream>>>(eoff, N_EDGES, esums, ecnt);
    scan_block<<<N_CHUNKS, 256, 0, stream>>>(ncnt, N_NODES, noff, nsums);
    scan_sums<<<1, 256, 0, stream>>>(nsums, N_CHUNKS);
    scan_add<<<(N_NODES + 256) / 256, 256, 0, stream>>>(noff, N_NODES, nsums, ncnt);
    csr_fill<<<(N_INC + 255) / 256, 256, 0, stream>>>(node_idx, edge_idx, ecnt, ncnt, elist, nlist);

    // ---- embedding ----
    embed_kernel<<<(N_NODES + 3) / 4, 256, 0, stream>>>(x, W_emb, b_emb, h16);

    // ---- 3 hypergraph conv layers: agg = P h; out = agg@W + b; BN; softplus ----
    for (int l = 0; l < NUM_LAYERS; ++l) {
        const float* Wl = conv_W + (size_t)l * NODE_DIM * NODE_DIM;
        const float* bl = conv_b + (size_t)l * NODE_DIM;

        edge_agg<<<(N_EDGES + 3) / 4, 256, 0, stream>>>(eoff, elist, (const half4*)h16,
                                                        binv, (half4*)efeat16);
        hipMemsetAsync(stats, 0, 128 * sizeof(float), stream);
        node_agg<<<1024, 256, 0, stream>>>(noff, nlist, (const half4*)efeat16, dinv,
                                           Wl, bl, outr16, stats);
        bnfin_kernel<<<1, 64, 0, stream>>>(stats, bn_g + (size_t)l * 64, bn_b + (size_t)l * 64, scsh);
        apply_kernel<<<(N_NODES * 16 + 255) / 256, 256, 0, stream>>>((const half4*)outr16, scsh,
                                                                     (half4*)h16);
    }

    // ---- pooling + head ----
    hipMemsetAsync(pooled, 0, (size_t)(N_GRAPHS * 64 + N_GRAPHS) * sizeof(float), stream);
    pool_kernel<<<(N_NODES * 64 + 255) / 256, 256, 0, stream>>>(h16, batch, pooled, cnt);
    head_kernel<<<N_GRAPHS, 128, 0, stream>>>(pooled, cnt, fc_W, fc_b, fco_W, fco_b, out);
}

// Round 5
// 1205.843 us; speedup vs baseline: 2.3902x; 1.2500x over previous
//
#include <hip/hip_runtime.h>
#include <hip/hip_fp16.h>
#include <math.h>

#define N_NODES   100000
#define N_EDGES   400000
#define N_INC     1600000
#define N_GRAPHS  512
#define ATOM_DIM  92
#define NODE_DIM  64
#define H_DIM     128
#define NUM_LAYERS 3
#define BN_EPS    1e-5f

#define NBUCK     391      // = ceil(400000/1024) = ceil(100000/256)
#define PCHUNK    16384    // items per partition block

struct alignas(8) half4 { __half2 a, b; };

__device__ __forceinline__ float softplus_f(float x) {
    return fmaxf(x, 0.f) + log1pf(expf(-fabsf(x)));
}

__device__ __forceinline__ float4 add4(float4 a, float4 b) {
    a.x += b.x; a.y += b.y; a.z += b.z; a.w += b.w; return a;
}
__device__ __forceinline__ float4 shflxor4(float4 v, int mask) {
    float4 r;
    r.x = __shfl_xor(v.x, mask); r.y = __shfl_xor(v.y, mask);
    r.z = __shfl_xor(v.z, mask); r.w = __shfl_xor(v.w, mask);
    return r;
}

// ---------------- embedding GEMM (fp32 in, fp16 out) ----------------

__global__ void embed_kernel(const float* __restrict__ x, const float* __restrict__ W,
                             const float* __restrict__ b, __half* __restrict__ h16) {
    __shared__ float xs[4][ATOM_DIM];
    int node0 = blockIdx.x * 4;
    int tid = threadIdx.x;
    for (int i = tid; i < 4 * ATOM_DIM; i += 256) {
        int nn = i / ATOM_DIM, kk = i - nn * ATOM_DIM;
        int n = node0 + nn;
        xs[nn][kk] = (n < N_NODES) ? x[(size_t)n * ATOM_DIM + kk] : 0.f;
    }
    __syncthreads();
    int nn = tid >> 6, f = tid & 63;
    int n = node0 + nn;
    if (n >= N_NODES) return;
    float acc = b[f];
    #pragma unroll
    for (int k = 0; k < ATOM_DIM; ++k)
        acc = fmaf(xs[nn][k], W[k * NODE_DIM + f], acc);
    h16[(size_t)n * NODE_DIM + f] = __float2half_rn(acc);
}

// ---------------- bucketed counting sort (CSR build, line-dense writes) ----------------

// global bucket histogram
__global__ void bucket_hist(const int* __restrict__ key, int n, int shift,
                            int* __restrict__ gcount) {
    __shared__ int h[NBUCK];
    int tid = threadIdx.x;
    for (int i = tid; i < NBUCK; i += 256) h[i] = 0;
    __syncthreads();
    for (int i = blockIdx.x * 256 + tid; i < n; i += gridDim.x * 256)
        atomicAdd(&h[key[i] >> shift], 1);
    __syncthreads();
    for (int i = tid; i < NBUCK; i += 256)
        if (h[i]) atomicAdd(&gcount[i], h[i]);
}

// scan NBUCK counts -> bbase[NBUCK+1]; init gcursor = bbase
__global__ void bucket_scan(const int* __restrict__ gcount, int* __restrict__ bbase,
                            int* __restrict__ gcursor) {
    __shared__ int sh[512];
    int tid = threadIdx.x;   // 512 threads
    int v = (tid < NBUCK) ? gcount[tid] : 0;
    sh[tid] = v;
    __syncthreads();
    for (int off = 1; off < 512; off <<= 1) {
        int t = (tid >= off) ? sh[tid - off] : 0;
        __syncthreads();
        sh[tid] += t;
        __syncthreads();
    }
    if (tid <= NBUCK) {
        int ex = (tid == 0) ? 0 : sh[tid - 1];
        bbase[tid] = ex;
        if (tid < NBUCK) gcursor[tid] = ex;
    }
}

// partition (key,payload) pairs into bucket-contiguous staging
__global__ void bucket_partition(const int* __restrict__ key, const int* __restrict__ pay,
                                 int n, int shift, int* __restrict__ gcursor,
                                 unsigned long long* __restrict__ staging) {
    __shared__ int h[NBUCK];
    __shared__ int cur[NBUCK];
    int tid = threadIdx.x;
    int base = blockIdx.x * PCHUNK;
    int end = base + PCHUNK; if (end > n) end = n;
    for (int i = tid; i < NBUCK; i += 256) h[i] = 0;
    __syncthreads();
    for (int i = base + tid; i < end; i += 256)
        atomicAdd(&h[key[i] >> shift], 1);
    __syncthreads();
    for (int i = tid; i < NBUCK; i += 256) {
        int c = h[i];
        cur[i] = c ? atomicAdd(&gcursor[i], c) : 0;
    }
    __syncthreads();
    for (int i = base + tid; i < end; i += 256) {
        int k = key[i];
        int pos = atomicAdd(&cur[k >> shift], 1);
        staging[pos] = ((unsigned long long)(unsigned)k << 32) | (unsigned)pay[i];
    }
}

// one block per bucket: per-id histogram -> offsets + 1/deg + in-bucket payload scatter
template<int RANGE>
__global__ void bucket_finalize(const unsigned long long* __restrict__ staging,
                                const int* __restrict__ bbase,
                                int nIds, float* __restrict__ inv,
                                int* __restrict__ off, int* __restrict__ list) {
    __shared__ int hist[RANGE];
    __shared__ int wsum[256];
    const int PER = RANGE / 256;
    int b = blockIdx.x, tid = threadIdx.x;
    int s = bbase[b], t = bbase[b + 1];
    int id0 = b * RANGE;
    for (int i = tid; i < RANGE; i += 256) hist[i] = 0;
    __syncthreads();
    for (int j = s + tid; j < t; j += 256) {
        int key = (int)(staging[j] >> 32);
        atomicAdd(&hist[key - id0], 1);
    }
    __syncthreads();
    // exclusive scan over RANGE entries (PER consecutive per thread)
    int base0 = tid * PER;
    int vals[PER];
    int local = 0;
    #pragma unroll
    for (int k = 0; k < PER; ++k) { vals[k] = hist[base0 + k]; local += vals[k]; }
    wsum[tid] = local;
    __syncthreads();
    for (int o = 1; o < 256; o <<= 1) {
        int tv = (tid >= o) ? wsum[tid - o] : 0;
        __syncthreads();
        wsum[tid] += tv;
        __syncthreads();
    }
    int run = wsum[tid] - local;
    #pragma unroll
    for (int k = 0; k < PER; ++k) {
        int id = id0 + base0 + k;
        int gpos = s + run;
        if (id < nIds) {
            off[id] = gpos;
            inv[id] = vals[k] > 0 ? 1.f / (float)vals[k] : 0.f;
        } else if (id == nIds) {
            off[nIds] = gpos;   // sentinel == N_INC in the last covering bucket
        }
        hist[base0 + k] = gpos;   // becomes the scatter cursor
        run += vals[k];
    }
    __syncthreads();
    for (int j = s + tid; j < t; j += 256) {
        unsigned long long it = staging[j];
        int key = (int)(it >> 32);
        int pos = atomicAdd(&hist[key - id0], 1);
        list[pos] = (int)(it & 0xffffffffu);
    }
}

// ---------------- gather aggregations (fp16 storage, fp32 math) ----------------

__global__ void edge_agg(const int* __restrict__ eoff, const int* __restrict__ elist,
                         const half4* __restrict__ h4, const float* __restrict__ binv,
                         half4* __restrict__ efeat4) {
    int e = blockIdx.x * 4 + (threadIdx.x >> 6);
    if (e >= N_EDGES) return;
    int lane = threadIdx.x & 63;
    int m = lane >> 4, q = lane & 15;    // member slot, feature quad
    int s = eoff[e], t = eoff[e + 1];
    float4 acc = {0.f, 0.f, 0.f, 0.f};
    for (int j = s + m; j < t; j += 4) {
        int n = __ldg(&elist[j]);
        half4 v = h4[(size_t)n * 16 + q];
        float2 lo = __half22float2(v.a), hi = __half22float2(v.b);
        acc.x += lo.x; acc.y += lo.y; acc.z += hi.x; acc.w += hi.y;
    }
    acc = add4(acc, shflxor4(acc, 16));
    acc = add4(acc, shflxor4(acc, 32));
    if (m == 0) {
        float bv = binv[e];
        half4 r;
        r.a = __floats2half2_rn(acc.x * bv, acc.y * bv);
        r.b = __floats2half2_rn(acc.z * bv, acc.w * bv);
        efeat4[(size_t)e * 16 + q] = r;
    }
}

__global__ void node_agg(const int* __restrict__ noff, const int* __restrict__ nlist,
                         const half4* __restrict__ efeat4, const float* __restrict__ dinv,
                         const float* __restrict__ W, const float* __restrict__ bvec,
                         __half* __restrict__ outr16, float* __restrict__ stats) {
    __shared__ float Ws[64 * 64];
    __shared__ float sA[4][64];
    __shared__ float sB[4][64];
    int tid = threadIdx.x;
    for (int i = tid; i < 64 * 64; i += 256) Ws[i] = W[i];
    __syncthreads();
    int wave = tid >> 6, lane = tid & 63;
    int slot = lane >> 4, q = lane & 15;
    float sa = 0.f, sb = 0.f;
    for (int n = blockIdx.x * 4 + wave; n < N_NODES; n += gridDim.x * 4) {
        int s = noff[n], t = noff[n + 1];
        float4 acc = {0.f, 0.f, 0.f, 0.f};
        for (int j = s + slot; j < t; j += 4) {
            int e = __ldg(&nlist[j]);
            half4 v = efeat4[(size_t)e * 16 + q];
            float2 lo = __half22float2(v.a), hi = __half22float2(v.b);
            acc.x += lo.x; acc.y += lo.y; acc.z += hi.x; acc.w += hi.y;
        }
        acc = add4(acc, shflxor4(acc, 16));
        acc = add4(acc, shflxor4(acc, 32));
        float dv = dinv[n];
        acc.x *= dv; acc.y *= dv; acc.z *= dv; acc.w *= dv;
        float out = bvec[lane];
        #pragma unroll
        for (int qq = 0; qq < 16; ++qq) {
            float4 av;
            av.x = __shfl(acc.x, qq); av.y = __shfl(acc.y, qq);
            av.z = __shfl(acc.z, qq); av.w = __shfl(acc.w, qq);
            out = fmaf(av.x, Ws[(4 * qq + 0) * 64 + lane], out);
            out = fmaf(av.y, Ws[(4 * qq + 1) * 64 + lane], out);
            out = fmaf(av.z, Ws[(4 * qq + 2) * 64 + lane], out);
            out = fmaf(av.w, Ws[(4 * qq + 3) * 64 + lane], out);
        }
        if (t == s) out = 0.f;   // isolated node: reference gives exactly 0
        outr16[(size_t)n * 64 + lane] = __float2half_rn(out);
        sa += out; sb += out * out;
    }
    sA[wave][lane] = sa; sB[wave][lane] = sb;
    __syncthreads();
    if (tid < 64) {
        float a = sA[0][tid] + sA[1][tid] + sA[2][tid] + sA[3][tid];
        float b = sB[0][tid] + sB[1][tid] + sB[2][tid] + sB[3][tid];
        atomicAdd(&stats[tid], a);
        atomicAdd(&stats[64 + tid], b);
    }
}

// ---------------- BN + softplus ----------------

__global__ void bnfin_kernel(const float* __restrict__ stats, const float* __restrict__ gamma,
                             const float* __restrict__ beta, float* __restrict__ scsh) {
    int f = threadIdx.x;
    if (f >= 64) return;
    const float invN = 1.f / (float)N_NODES;
    float mean = stats[f] * invN;
    float var  = stats[64 + f] * invN - mean * mean;
    var = fmaxf(var, 0.f);
    float sc = gamma[f] * rsqrtf(var + BN_EPS);
    scsh[f]      = sc;
    scsh[64 + f] = beta[f] - mean * sc;
}

__global__ void apply_kernel(const half4* __restrict__ outr4, const float* __restrict__ scsh,
                             half4* __restrict__ h4) {
    int gid = blockIdx.x * 256 + threadIdx.x;   // over N_NODES*16 quads
    if (gid >= N_NODES * 16) return;
    int qq = gid & 15;
    half4 v = outr4[gid];
    float2 lo = __half22float2(v.a), hi = __half22float2(v.b);
    float4 sc = ((const float4*)scsh)[qq];
    float4 sh = ((const float4*)(scsh + 64))[qq];
    half4 r;
    r.a = __floats2half2_rn(softplus_f(fmaf(lo.x, sc.x, sh.x)),
                            softplus_f(fmaf(lo.y, sc.y, sh.y)));
    r.b = __floats2half2_rn(softplus_f(fmaf(hi.x, sc.z, sh.z)),
                            softplus_f(fmaf(hi.y, sc.w, sh.w)));
    h4[gid] = r;
}

// ---------------- pooling + head ----------------

__global__ void pool_kernel(const __half* __restrict__ h16, const int* __restrict__ batch,
                            float* __restrict__ pooled, float* __restrict__ cnt) {
    int gid = blockIdx.x * 256 + threadIdx.x;   // over N_NODES*64
    int f = gid & 63, n = gid >> 6;
    if (n >= N_NODES) return;
    int g = batch[n];
    atomicAdd(&pooled[(size_t)g * 64 + f], __half2float(h16[gid]));
    if (f == 0) atomicAdd(&cnt[g], 1.f);
}

__global__ void head_kernel(const float* __restrict__ pooled, const float* __restrict__ cnt,
                            const float* __restrict__ fcW, const float* __restrict__ fcb,
                            const float* __restrict__ fcoW, const float* __restrict__ fcob,
                            float* __restrict__ out) {
    __shared__ float p[64];
    __shared__ float red[128];
    int g = blockIdx.x, tid = threadIdx.x;   // 128 threads
    if (tid < 64) {
        float c = fmaxf(cnt[g], 1.f);
        p[tid] = softplus_f(pooled[(size_t)g * 64 + tid] / c);
    }
    __syncthreads();
    float acc = fcb[tid];
    #pragma unroll
    for (int k = 0; k < 64; ++k)
        acc = fmaf(p[k], fcW[k * H_DIM + tid], acc);
    float h1 = softplus_f(acc);
    red[tid] = h1 * fcoW[tid];
    __syncthreads();
    for (int s = 64; s > 0; s >>= 1) {
        if (tid < s) red[tid] += red[tid + s];
        __syncthreads();
    }
    if (tid == 0) out[g] = red[0] + fcob[0];
}

// ---------------- launch ----------------

extern "C" void kernel_launch(void* const* d_in, const int* in_sizes, int n_in,
                              void* d_out, int out_size, void* d_ws, size_t ws_size,
                              hipStream_t stream) {
    const float* x      = (const float*)d_in[0];
    const float* W_emb  = (const float*)d_in[1];
    const float* b_emb  = (const float*)d_in[2];
    const float* conv_W = (const float*)d_in[3];
    const float* conv_b = (const float*)d_in[4];
    const float* bn_g   = (const float*)d_in[5];
    const float* bn_b   = (const float*)d_in[6];
    const float* fc_W   = (const float*)d_in[7];
    const float* fc_b   = (const float*)d_in[8];
    const float* fco_W  = (const float*)d_in[9];
    const float* fco_b  = (const float*)d_in[10];
    const int* node_idx = (const int*)d_in[11];
    const int* edge_idx = (const int*)d_in[12];
    const int* batch    = (const int*)d_in[13];
    float* out = (float*)d_out;

    // ---- workspace layout ----
    __half* h16    = (__half*)d_ws;                            // 6.4M halves
    __half* outr16 = h16    + (size_t)N_NODES * 64;            // 6.4M halves
    __half* efeat16= outr16 + (size_t)N_NODES * 64;            // 25.6M halves
    unsigned long long* staging = (unsigned long long*)(efeat16 + (size_t)N_EDGES * 64); // 1.6M u64
    float* binv    = (float*)(staging + N_INC);                // 400K
    float* dinv    = binv   + N_EDGES;                         // 100K
    float* stats   = dinv   + N_NODES;                         // 128
    float* scsh    = stats  + 128;                             // 128
    float* pooled  = scsh   + 128;                             // 32768
    float* cnt     = pooled + (size_t)N_GRAPHS * 64;           // 512
    int*   eoff    = (int*)(cnt + N_GRAPHS);                   // 400K+1
    int*   noff    = eoff  + N_EDGES + 1;                      // 100K+1
    int*   gcountE = noff  + N_NODES + 1;                      // NBUCK
    int*   gcountN = gcountE + NBUCK;                          // NBUCK
    int*   bbaseE  = gcountN + NBUCK;                          // NBUCK+1
    int*   bbaseN  = bbaseE + NBUCK + 1;                       // NBUCK+1
    int*   gcurE   = bbaseN + NBUCK + 1;                       // NBUCK
    int*   gcurN   = gcurE + NBUCK;                            // NBUCK
    int*   elist   = gcurN + NBUCK;                            // 1.6M
    int*   nlist   = elist + N_INC;                            // 1.6M

    // ---- CSR build: two bucketed counting sorts ----
    hipMemsetAsync(gcountE, 0, 2 * NBUCK * sizeof(int), stream);
    // edge-keyed sort -> eoff, binv, elist
    bucket_hist<<<200, 256, 0, stream>>>(edge_idx, N_INC, 10, gcountE);
    bucket_scan<<<1, 512, 0, stream>>>(gcountE, bbaseE, gcurE);
    bucket_partition<<<(N_INC + PCHUNK - 1) / PCHUNK, 256, 0, stream>>>(
        edge_idx, node_idx, N_INC, 10, gcurE, staging);
    bucket_finalize<1024><<<NBUCK, 256, 0, stream>>>(staging, bbaseE, N_EDGES, binv, eoff, elist);
    // node-keyed sort -> noff, dinv, nlist
    bucket_hist<<<200, 256, 0, stream>>>(node_idx, N_INC, 8, gcountN);
    bucket_scan<<<1, 512, 0, stream>>>(gcountN, bbaseN, gcurN);
    bucket_partition<<<(N_INC + PCHUNK - 1) / PCHUNK, 256, 0, stream>>>(
        node_idx, edge_idx, N_INC, 8, gcurN, staging);
    bucket_finalize<256><<<NBUCK, 256, 0, stream>>>(staging, bbaseN, N_NODES, dinv, noff, nlist);

    // ---- embedding ----
    embed_kernel<<<(N_NODES + 3) / 4, 256, 0, stream>>>(x, W_emb, b_emb, h16);

    // ---- 3 hypergraph conv layers: agg = P h; out = agg@W + b; BN; softplus ----
    for (int l = 0; l < NUM_LAYERS; ++l) {
        const float* Wl = conv_W + (size_t)l * NODE_DIM * NODE_DIM;
        const float* bl = conv_b + (size_t)l * NODE_DIM;

        edge_agg<<<(N_EDGES + 3) / 4, 256, 0, stream>>>(eoff, elist, (const half4*)h16,
                                                        binv, (half4*)efeat16);
        hipMemsetAsync(stats, 0, 128 * sizeof(float), stream);
        node_agg<<<1024, 256, 0, stream>>>(noff, nlist, (const half4*)efeat16, dinv,
                                           Wl, bl, outr16, stats);
        bnfin_kernel<<<1, 64, 0, stream>>>(stats, bn_g + (size_t)l * 64, bn_b + (size_t)l * 64, scsh);
        apply_kernel<<<(N_NODES * 16 + 255) / 256, 256, 0, stream>>>((const half4*)outr16, scsh,
                                                                     (half4*)h16);
    }

    // ---- pooling + head ----
    hipMemsetAsync(pooled, 0, (size_t)(N_GRAPHS * 64 + N_GRAPHS) * sizeof(float), stream);
    pool_kernel<<<(N_NODES * 64 + 255) / 256, 256, 0, stream>>>(h16, batch, pooled, cnt);
    head_kernel<<<N_GRAPHS, 128, 0, stream>>>(pooled, cnt, fc_W, fc_b, fco_W, fco_b, out);
}

// Round 6
// 1044.927 us; speedup vs baseline: 2.7583x; 1.1540x over previous
//
#include <hip/hip_runtime.h>
#include <hip/hip_fp16.h>
#include <math.h>

#define N_NODES   100000
#define N_EDGES   400000
#define N_INC     1600000
#define N_GRAPHS  512
#define ATOM_DIM  92
#define NODE_DIM  64
#define H_DIM     128
#define NUM_LAYERS 3
#define BN_EPS    1e-5f

#define NBUCK     391      // = ceil(400000/1024) = ceil(100000/256)
#define PCHUNK    16384    // items per partition block

struct alignas(8) half4 { __half2 a, b; };

__device__ __forceinline__ float softplus_f(float x) {
    return fmaxf(x, 0.f) + log1pf(expf(-fabsf(x)));
}

__device__ __forceinline__ float4 add4(float4 a, float4 b) {
    a.x += b.x; a.y += b.y; a.z += b.z; a.w += b.w; return a;
}
__device__ __forceinline__ float4 shflxor4(float4 v, int mask) {
    float4 r;
    r.x = __shfl_xor(v.x, mask); r.y = __shfl_xor(v.y, mask);
    r.z = __shfl_xor(v.z, mask); r.w = __shfl_xor(v.w, mask);
    return r;
}

// ---------------- embedding GEMM (fp32 in, fp16 out) ----------------

__global__ void embed_kernel(const float* __restrict__ x, const float* __restrict__ W,
                             const float* __restrict__ b, __half* __restrict__ h16) {
    __shared__ float xs[4][ATOM_DIM];
    int node0 = blockIdx.x * 4;
    int tid = threadIdx.x;
    for (int i = tid; i < 4 * ATOM_DIM; i += 256) {
        int nn = i / ATOM_DIM, kk = i - nn * ATOM_DIM;
        int n = node0 + nn;
        xs[nn][kk] = (n < N_NODES) ? x[(size_t)n * ATOM_DIM + kk] : 0.f;
    }
    __syncthreads();
    int nn = tid >> 6, f = tid & 63;
    int n = node0 + nn;
    if (n >= N_NODES) return;
    float acc = b[f];
    #pragma unroll
    for (int k = 0; k < ATOM_DIM; ++k)
        acc = fmaf(xs[nn][k], W[k * NODE_DIM + f], acc);
    h16[(size_t)n * NODE_DIM + f] = __float2half_rn(acc);
}

// ---------------- bucketed counting sort (CSR build, line-dense writes) ----------------

__global__ void bucket_hist(const int* __restrict__ key, int n, int shift,
                            int* __restrict__ gcount) {
    __shared__ int h[NBUCK];
    int tid = threadIdx.x;
    for (int i = tid; i < NBUCK; i += 256) h[i] = 0;
    __syncthreads();
    for (int i = blockIdx.x * 256 + tid; i < n; i += gridDim.x * 256)
        atomicAdd(&h[key[i] >> shift], 1);
    __syncthreads();
    for (int i = tid; i < NBUCK; i += 256)
        if (h[i]) atomicAdd(&gcount[i], h[i]);
}

__global__ void bucket_scan(const int* __restrict__ gcount, int* __restrict__ bbase,
                            int* __restrict__ gcursor) {
    __shared__ int sh[512];
    int tid = threadIdx.x;   // 512 threads
    int v = (tid < NBUCK) ? gcount[tid] : 0;
    sh[tid] = v;
    __syncthreads();
    for (int off = 1; off < 512; off <<= 1) {
        int t = (tid >= off) ? sh[tid - off] : 0;
        __syncthreads();
        sh[tid] += t;
        __syncthreads();
    }
    if (tid <= NBUCK) {
        int ex = (tid == 0) ? 0 : sh[tid - 1];
        bbase[tid] = ex;
        if (tid < NBUCK) gcursor[tid] = ex;
    }
}

__global__ void bucket_partition(const int* __restrict__ key, const int* __restrict__ pay,
                                 int n, int shift, int* __restrict__ gcursor,
                                 unsigned long long* __restrict__ staging) {
    __shared__ int h[NBUCK];
    __shared__ int cur[NBUCK];
    int tid = threadIdx.x;
    int base = blockIdx.x * PCHUNK;
    int end = base + PCHUNK; if (end > n) end = n;
    for (int i = tid; i < NBUCK; i += 256) h[i] = 0;
    __syncthreads();
    for (int i = base + tid; i < end; i += 256)
        atomicAdd(&h[key[i] >> shift], 1);
    __syncthreads();
    for (int i = tid; i < NBUCK; i += 256) {
        int c = h[i];
        cur[i] = c ? atomicAdd(&gcursor[i], c) : 0;
    }
    __syncthreads();
    for (int i = base + tid; i < end; i += 256) {
        int k = key[i];
        int pos = atomicAdd(&cur[k >> shift], 1);
        staging[pos] = ((unsigned long long)(unsigned)k << 32) | (unsigned)pay[i];
    }
}

template<int RANGE>
__global__ void bucket_finalize(const unsigned long long* __restrict__ staging,
                                const int* __restrict__ bbase,
                                int nIds, float* __restrict__ inv,
                                int* __restrict__ off, int* __restrict__ list) {
    __shared__ int hist[RANGE];
    __shared__ int wsum[256];
    const int PER = RANGE / 256;
    int b = blockIdx.x, tid = threadIdx.x;
    int s = bbase[b], t = bbase[b + 1];
    int id0 = b * RANGE;
    for (int i = tid; i < RANGE; i += 256) hist[i] = 0;
    __syncthreads();
    for (int j = s + tid; j < t; j += 256) {
        int key = (int)(staging[j] >> 32);
        atomicAdd(&hist[key - id0], 1);
    }
    __syncthreads();
    int base0 = tid * PER;
    int vals[PER];
    int local = 0;
    #pragma unroll
    for (int k = 0; k < PER; ++k) { vals[k] = hist[base0 + k]; local += vals[k]; }
    wsum[tid] = local;
    __syncthreads();
    for (int o = 1; o < 256; o <<= 1) {
        int tv = (tid >= o) ? wsum[tid - o] : 0;
        __syncthreads();
        wsum[tid] += tv;
        __syncthreads();
    }
    int run = wsum[tid] - local;
    #pragma unroll
    for (int k = 0; k < PER; ++k) {
        int id = id0 + base0 + k;
        int gpos = s + run;
        if (id < nIds) {
            off[id] = gpos;
            inv[id] = vals[k] > 0 ? 1.f / (float)vals[k] : 0.f;
        } else if (id == nIds) {
            off[nIds] = gpos;
        }
        hist[base0 + k] = gpos;
        run += vals[k];
    }
    __syncthreads();
    for (int j = s + tid; j < t; j += 256) {
        unsigned long long it = staging[j];
        int key = (int)(it >> 32);
        int pos = atomicAdd(&hist[key - id0], 1);
        list[pos] = (int)(it & 0xffffffffu);
    }
}

// ---------------- gather aggregations (fp16 storage, fp32 math) ----------------

__global__ void edge_agg(const int* __restrict__ eoff, const int* __restrict__ elist,
                         const half4* __restrict__ h4, const float* __restrict__ binv,
                         half4* __restrict__ efeat4) {
    int e = blockIdx.x * 4 + (threadIdx.x >> 6);
    if (e >= N_EDGES) return;
    int lane = threadIdx.x & 63;
    int m = lane >> 4, q = lane & 15;    // member slot, feature quad
    int s = eoff[e], t = eoff[e + 1];
    float4 acc = {0.f, 0.f, 0.f, 0.f};
    for (int j = s + m; j < t; j += 4) {
        int n = __ldg(&elist[j]);
        half4 v = h4[(size_t)n * 16 + q];
        float2 lo = __half22float2(v.a), hi = __half22float2(v.b);
        acc.x += lo.x; acc.y += lo.y; acc.z += hi.x; acc.w += hi.y;
    }
    acc = add4(acc, shflxor4(acc, 16));
    acc = add4(acc, shflxor4(acc, 32));
    if (m == 0) {
        float bv = binv[e];
        half4 r;
        r.a = __floats2half2_rn(acc.x * bv, acc.y * bv);
        r.b = __floats2half2_rn(acc.z * bv, acc.w * bv);
        efeat4[(size_t)e * 16 + q] = r;
    }
}

__global__ void node_agg(const int* __restrict__ noff, const int* __restrict__ nlist,
                         const half4* __restrict__ efeat4, const float* __restrict__ dinv,
                         const float* __restrict__ W, const float* __restrict__ bvec,
                         __half* __restrict__ outr16, float* __restrict__ stats) {
    __shared__ float Ws[64 * 64];
    __shared__ float sA[4][64];
    __shared__ float sB[4][64];
    int tid = threadIdx.x;
    for (int i = tid; i < 64 * 64; i += 256) Ws[i] = W[i];
    __syncthreads();
    int wave = tid >> 6, lane = tid & 63;
    int slot = lane >> 4, q = lane & 15;
    float sa = 0.f, sb = 0.f;
    for (int n = blockIdx.x * 4 + wave; n < N_NODES; n += gridDim.x * 4) {
        int s = noff[n], t = noff[n + 1];
        float4 acc = {0.f, 0.f, 0.f, 0.f};
        for (int j = s + slot; j < t; j += 4) {
            int e = __ldg(&nlist[j]);
            half4 v = efeat4[(size_t)e * 16 + q];
            float2 lo = __half22float2(v.a), hi = __half22float2(v.b);
            acc.x += lo.x; acc.y += lo.y; acc.z += hi.x; acc.w += hi.y;
        }
        acc = add4(acc, shflxor4(acc, 16));
        acc = add4(acc, shflxor4(acc, 32));
        float dv = dinv[n];
        acc.x *= dv; acc.y *= dv; acc.z *= dv; acc.w *= dv;
        float out = bvec[lane];
        #pragma unroll
        for (int qq = 0; qq < 16; ++qq) {
            float4 av;
            av.x = __shfl(acc.x, qq); av.y = __shfl(acc.y, qq);
            av.z = __shfl(acc.z, qq); av.w = __shfl(acc.w, qq);
            out = fmaf(av.x, Ws[(4 * qq + 0) * 64 + lane], out);
            out = fmaf(av.y, Ws[(4 * qq + 1) * 64 + lane], out);
            out = fmaf(av.z, Ws[(4 * qq + 2) * 64 + lane], out);
            out = fmaf(av.w, Ws[(4 * qq + 3) * 64 + lane], out);
        }
        if (t == s) out = 0.f;   // isolated node: reference gives exactly 0
        outr16[(size_t)n * 64 + lane] = __float2half_rn(out);
        sa += out; sb += out * out;
    }
    sA[wave][lane] = sa; sB[wave][lane] = sb;
    __syncthreads();
    if (tid < 64) {
        float a = sA[0][tid] + sA[1][tid] + sA[2][tid] + sA[3][tid];
        float b = sB[0][tid] + sB[1][tid] + sB[2][tid] + sB[3][tid];
        atomicAdd(&stats[tid], a);
        atomicAdd(&stats[64 + tid], b);
    }
}

// ---------------- BN + softplus ----------------

__global__ void bnfin_kernel(const float* __restrict__ stats, const float* __restrict__ gamma,
                             const float* __restrict__ beta, float* __restrict__ scsh) {
    int f = threadIdx.x;
    if (f >= 64) return;
    const float invN = 1.f / (float)N_NODES;
    float mean = stats[f] * invN;
    float var  = stats[64 + f] * invN - mean * mean;
    var = fmaxf(var, 0.f);
    float sc = gamma[f] * rsqrtf(var + BN_EPS);
    scsh[f]      = sc;
    scsh[64 + f] = beta[f] - mean * sc;
}

__global__ void apply_kernel(const half4* __restrict__ outr4, const float* __restrict__ scsh,
                             half4* __restrict__ h4) {
    int gid = blockIdx.x * 256 + threadIdx.x;   // over N_NODES*16 quads
    if (gid >= N_NODES * 16) return;
    int qq = gid & 15;
    half4 v = outr4[gid];
    float2 lo = __half22float2(v.a), hi = __half22float2(v.b);
    float4 sc = ((const float4*)scsh)[qq];
    float4 sh = ((const float4*)(scsh + 64))[qq];
    half4 r;
    r.a = __floats2half2_rn(softplus_f(fmaf(lo.x, sc.x, sh.x)),
                            softplus_f(fmaf(lo.y, sc.y, sh.y)));
    r.b = __floats2half2_rn(softplus_f(fmaf(hi.x, sc.z, sh.z)),
                            softplus_f(fmaf(hi.y, sc.w, sh.w)));
    h4[gid] = r;
}

// ---------------- pooling + head (batch is sorted -> segmented gather) ----------------

// goff[g] = lower_bound(batch, g), g in [0, N_GRAPHS]
__global__ void graph_bounds(const int* __restrict__ batch, int* __restrict__ goff) {
    int g = blockIdx.x * 256 + threadIdx.x;
    if (g > N_GRAPHS) return;
    int lo = 0, hi = N_NODES;
    while (lo < hi) {
        int mid = (lo + hi) >> 1;
        if (batch[mid] < g) lo = mid + 1; else hi = mid;
    }
    goff[g] = lo;
}

// one block (256 thr) per graph: mean-pool -> softplus -> fc(64->128)+softplus -> fco(128->1)
__global__ void pool_head_kernel(const __half* __restrict__ h16, const int* __restrict__ goff,
                                 const float* __restrict__ fcW, const float* __restrict__ fcb,
                                 const float* __restrict__ fcoW, const float* __restrict__ fcob,
                                 float* __restrict__ out) {
    __shared__ float part[4][64];
    __shared__ float p[64];
    __shared__ float red[128];
    int g = blockIdx.x, tid = threadIdx.x;
    int s = goff[g], t = goff[g + 1];
    int f = tid & 63, r = tid >> 6;
    float acc = 0.f;
    for (int n = s + r; n < t; n += 4)
        acc += __half2float(h16[(size_t)n * 64 + f]);
    part[r][f] = acc;
    __syncthreads();
    if (tid < 64) {
        float v = part[0][tid] + part[1][tid] + part[2][tid] + part[3][tid];
        float c = fmaxf((float)(t - s), 1.f);
        p[tid] = softplus_f(v / c);
    }
    __syncthreads();
    if (tid < 128) {
        float a = fcb[tid];
        #pragma unroll
        for (int k = 0; k < 64; ++k)
            a = fmaf(p[k], fcW[k * H_DIM + tid], a);
        red[tid] = softplus_f(a) * fcoW[tid];
    }
    __syncthreads();
    for (int st = 64; st > 0; st >>= 1) {
        if (tid < st) red[tid] += red[tid + st];
        __syncthreads();
    }
    if (tid == 0) out[g] = red[0] + fcob[0];
}

// ---------------- launch ----------------

extern "C" void kernel_launch(void* const* d_in, const int* in_sizes, int n_in,
                              void* d_out, int out_size, void* d_ws, size_t ws_size,
                              hipStream_t stream) {
    const float* x      = (const float*)d_in[0];
    const float* W_emb  = (const float*)d_in[1];
    const float* b_emb  = (const float*)d_in[2];
    const float* conv_W = (const float*)d_in[3];
    const float* conv_b = (const float*)d_in[4];
    const float* bn_g   = (const float*)d_in[5];
    const float* bn_b   = (const float*)d_in[6];
    const float* fc_W   = (const float*)d_in[7];
    const float* fc_b   = (const float*)d_in[8];
    const float* fco_W  = (const float*)d_in[9];
    const float* fco_b  = (const float*)d_in[10];
    const int* node_idx = (const int*)d_in[11];
    const int* edge_idx = (const int*)d_in[12];
    const int* batch    = (const int*)d_in[13];
    float* out = (float*)d_out;

    // ---- workspace layout ----
    __half* h16    = (__half*)d_ws;                            // 6.4M halves
    __half* outr16 = h16    + (size_t)N_NODES * 64;            // 6.4M halves
    __half* efeat16= outr16 + (size_t)N_NODES * 64;            // 25.6M halves
    unsigned long long* staging = (unsigned long long*)(efeat16 + (size_t)N_EDGES * 64); // 1.6M u64
    float* binv    = (float*)(staging + N_INC);                // 400K
    float* dinv    = binv   + N_EDGES;                         // 100K
    float* stats   = dinv   + N_NODES;                         // 128
    float* scsh    = stats  + 128;                             // 128
    int*   goff    = (int*)(scsh + 128);                       // N_GRAPHS+1
    int*   eoff    = goff  + N_GRAPHS + 1;                     // 400K+1
    int*   noff    = eoff  + N_EDGES + 1;                      // 100K+1
    int*   gcountE = noff  + N_NODES + 1;                      // NBUCK
    int*   gcountN = gcountE + NBUCK;                          // NBUCK
    int*   bbaseE  = gcountN + NBUCK;                          // NBUCK+1
    int*   bbaseN  = bbaseE + NBUCK + 1;                       // NBUCK+1
    int*   gcurE   = bbaseN + NBUCK + 1;                       // NBUCK
    int*   gcurN   = gcurE + NBUCK;                            // NBUCK
    int*   elist   = gcurN + NBUCK;                            // 1.6M
    int*   nlist   = elist + N_INC;                            // 1.6M

    // ---- CSR build: two bucketed counting sorts ----
    hipMemsetAsync(gcountE, 0, 2 * NBUCK * sizeof(int), stream);
    bucket_hist<<<200, 256, 0, stream>>>(edge_idx, N_INC, 10, gcountE);
    bucket_scan<<<1, 512, 0, stream>>>(gcountE, bbaseE, gcurE);
    bucket_partition<<<(N_INC + PCHUNK - 1) / PCHUNK, 256, 0, stream>>>(
        edge_idx, node_idx, N_INC, 10, gcurE, staging);
    bucket_finalize<1024><<<NBUCK, 256, 0, stream>>>(staging, bbaseE, N_EDGES, binv, eoff, elist);
    bucket_hist<<<200, 256, 0, stream>>>(node_idx, N_INC, 8, gcountN);
    bucket_scan<<<1, 512, 0, stream>>>(gcountN, bbaseN, gcurN);
    bucket_partition<<<(N_INC + PCHUNK - 1) / PCHUNK, 256, 0, stream>>>(
        node_idx, edge_idx, N_INC, 8, gcurN, staging);
    bucket_finalize<256><<<NBUCK, 256, 0, stream>>>(staging, bbaseN, N_NODES, dinv, noff, nlist);

    // ---- graph boundaries (batch is sorted) ----
    graph_bounds<<<(N_GRAPHS + 1 + 255) / 256, 256, 0, stream>>>(batch, goff);

    // ---- embedding ----
    embed_kernel<<<(N_NODES + 3) / 4, 256, 0, stream>>>(x, W_emb, b_emb, h16);

    // ---- 3 hypergraph conv layers: agg = P h; out = agg@W + b; BN; softplus ----
    for (int l = 0; l < NUM_LAYERS; ++l) {
        const float* Wl = conv_W + (size_t)l * NODE_DIM * NODE_DIM;
        const float* bl = conv_b + (size_t)l * NODE_DIM;

        edge_agg<<<(N_EDGES + 3) / 4, 256, 0, stream>>>(eoff, elist, (const half4*)h16,
                                                        binv, (half4*)efeat16);
        hipMemsetAsync(stats, 0, 128 * sizeof(float), stream);
        node_agg<<<1024, 256, 0, stream>>>(noff, nlist, (const half4*)efeat16, dinv,
                                           Wl, bl, outr16, stats);
        bnfin_kernel<<<1, 64, 0, stream>>>(stats, bn_g + (size_t)l * 64, bn_b + (size_t)l * 64, scsh);
        apply_kernel<<<(N_NODES * 16 + 255) / 256, 256, 0, stream>>>((const half4*)outr16, scsh,
                                                                     (half4*)h16);
    }

    // ---- fused pooling + head ----
    pool_head_kernel<<<N_GRAPHS, 256, 0, stream>>>(h16, goff, fc_W, fc_b, fco_W, fco_b, out);
}

// Round 7
// 896.660 us; speedup vs baseline: 3.2144x; 1.1654x over previous
//
#include <hip/hip_runtime.h>
#include <hip/hip_fp16.h>
#include <math.h>

#define N_NODES   100000
#define N_EDGES   400000
#define N_INC     1600000
#define N_GRAPHS  512
#define ATOM_DIM  92
#define NODE_DIM  64
#define H_DIM     128
#define NUM_LAYERS 3
#define BN_EPS    1e-5f

#define NBUCK     391      // = ceil(400000/1024) = ceil(100000/256)
#define PCHUNK    16384    // items per partition block

struct alignas(8)  half4 { __half2 a, b; };
struct alignas(16) half8 { __half2 a, b, c, d; };
typedef __attribute__((ext_vector_type(8))) float float8;

__device__ __forceinline__ float softplus_f(float x) {
    return fmaxf(x, 0.f) + log1pf(expf(-fabsf(x)));
}

__device__ __forceinline__ float8 cvt8(half8 v) {
    float2 p0 = __half22float2(v.a), p1 = __half22float2(v.b);
    float2 p2 = __half22float2(v.c), p3 = __half22float2(v.d);
    float8 r;
    r[0] = p0.x; r[1] = p0.y; r[2] = p1.x; r[3] = p1.y;
    r[4] = p2.x; r[5] = p2.y; r[6] = p3.x; r[7] = p3.y;
    return r;
}
__device__ __forceinline__ half8 cvt16(float8 v) {
    half8 r;
    r.a = __floats2half2_rn(v[0], v[1]);
    r.b = __floats2half2_rn(v[2], v[3]);
    r.c = __floats2half2_rn(v[4], v[5]);
    r.d = __floats2half2_rn(v[6], v[7]);
    return r;
}
__device__ __forceinline__ float8 shflxor8(float8 v, int mask) {
    float8 r;
    #pragma unroll
    for (int i = 0; i < 8; ++i) r[i] = __shfl_xor(v[i], mask);
    return r;
}

// ---------------- embedding GEMM (fp32 in, fp16 out) ----------------

__global__ void embed_kernel(const float* __restrict__ x, const float* __restrict__ W,
                             const float* __restrict__ b, __half* __restrict__ h16) {
    __shared__ float xs[4][ATOM_DIM];
    int node0 = blockIdx.x * 4;
    int tid = threadIdx.x;
    for (int i = tid; i < 4 * ATOM_DIM; i += 256) {
        int nn = i / ATOM_DIM, kk = i - nn * ATOM_DIM;
        int n = node0 + nn;
        xs[nn][kk] = (n < N_NODES) ? x[(size_t)n * ATOM_DIM + kk] : 0.f;
    }
    __syncthreads();
    int nn = tid >> 6, f = tid & 63;
    int n = node0 + nn;
    if (n >= N_NODES) return;
    float acc = b[f];
    #pragma unroll
    for (int k = 0; k < ATOM_DIM; ++k)
        acc = fmaf(xs[nn][k], W[k * NODE_DIM + f], acc);
    h16[(size_t)n * NODE_DIM + f] = __float2half_rn(acc);
}

// ---------------- bucketed counting sort (CSR build, line-dense writes) ----------------

__global__ void bucket_hist(const int* __restrict__ key, int n, int shift,
                            int* __restrict__ gcount) {
    __shared__ int h[NBUCK];
    int tid = threadIdx.x;
    for (int i = tid; i < NBUCK; i += 256) h[i] = 0;
    __syncthreads();
    for (int i = blockIdx.x * 256 + tid; i < n; i += gridDim.x * 256)
        atomicAdd(&h[key[i] >> shift], 1);
    __syncthreads();
    for (int i = tid; i < NBUCK; i += 256)
        if (h[i]) atomicAdd(&gcount[i], h[i]);
}

__global__ void bucket_scan(const int* __restrict__ gcount, int* __restrict__ bbase,
                            int* __restrict__ gcursor) {
    __shared__ int sh[512];
    int tid = threadIdx.x;   // 512 threads
    int v = (tid < NBUCK) ? gcount[tid] : 0;
    sh[tid] = v;
    __syncthreads();
    for (int off = 1; off < 512; off <<= 1) {
        int t = (tid >= off) ? sh[tid - off] : 0;
        __syncthreads();
        sh[tid] += t;
        __syncthreads();
    }
    if (tid <= NBUCK) {
        int ex = (tid == 0) ? 0 : sh[tid - 1];
        bbase[tid] = ex;
        if (tid < NBUCK) gcursor[tid] = ex;
    }
}

__global__ void bucket_partition(const int* __restrict__ key, const int* __restrict__ pay,
                                 int n, int shift, int* __restrict__ gcursor,
                                 unsigned long long* __restrict__ staging) {
    __shared__ int h[NBUCK];
    __shared__ int cur[NBUCK];
    int tid = threadIdx.x;
    int base = blockIdx.x * PCHUNK;
    int end = base + PCHUNK; if (end > n) end = n;
    for (int i = tid; i < NBUCK; i += 256) h[i] = 0;
    __syncthreads();
    for (int i = base + tid; i < end; i += 256)
        atomicAdd(&h[key[i] >> shift], 1);
    __syncthreads();
    for (int i = tid; i < NBUCK; i += 256) {
        int c = h[i];
        cur[i] = c ? atomicAdd(&gcursor[i], c) : 0;
    }
    __syncthreads();
    for (int i = base + tid; i < end; i += 256) {
        int k = key[i];
        int pos = atomicAdd(&cur[k >> shift], 1);
        staging[pos] = ((unsigned long long)(unsigned)k << 32) | (unsigned)pay[i];
    }
}

template<int RANGE>
__global__ void bucket_finalize(const unsigned long long* __restrict__ staging,
                                const int* __restrict__ bbase,
                                int nIds, float* __restrict__ inv,
                                int* __restrict__ off, int* __restrict__ list) {
    __shared__ int hist[RANGE];
    __shared__ int wsum[256];
    const int PER = RANGE / 256;
    int b = blockIdx.x, tid = threadIdx.x;
    int s = bbase[b], t = bbase[b + 1];
    int id0 = b * RANGE;
    for (int i = tid; i < RANGE; i += 256) hist[i] = 0;
    __syncthreads();
    for (int j = s + tid; j < t; j += 256) {
        int key = (int)(staging[j] >> 32);
        atomicAdd(&hist[key - id0], 1);
    }
    __syncthreads();
    int base0 = tid * PER;
    int vals[PER];
    int local = 0;
    #pragma unroll
    for (int k = 0; k < PER; ++k) { vals[k] = hist[base0 + k]; local += vals[k]; }
    wsum[tid] = local;
    __syncthreads();
    for (int o = 1; o < 256; o <<= 1) {
        int tv = (tid >= o) ? wsum[tid - o] : 0;
        __syncthreads();
        wsum[tid] += tv;
        __syncthreads();
    }
    int run = wsum[tid] - local;
    #pragma unroll
    for (int k = 0; k < PER; ++k) {
        int id = id0 + base0 + k;
        int gpos = s + run;
        if (id < nIds) {
            off[id] = gpos;
            inv[id] = vals[k] > 0 ? 1.f / (float)vals[k] : 0.f;
        } else if (id == nIds) {
            off[nIds] = gpos;
        }
        hist[base0 + k] = gpos;
        run += vals[k];
    }
    __syncthreads();
    for (int j = s + tid; j < t; j += 256) {
        unsigned long long it = staging[j];
        int key = (int)(it >> 32);
        int pos = atomicAdd(&hist[key - id0], 1);
        list[pos] = (int)(it & 0xffffffffu);
    }
}

// ---------------- gather aggregations (fp16 storage, fp32 math, 16B/lane) ----------------

// 2 edges per wave: half-wave = 4 member slots x 8 feature-octets
__global__ void edge_agg(const int* __restrict__ eoff, const int* __restrict__ elist,
                         const half8* __restrict__ h8, const float* __restrict__ binv,
                         half8* __restrict__ efeat8) {
    int e = blockIdx.x * 8 + (threadIdx.x >> 5);
    if (e >= N_EDGES) return;
    int hl = threadIdx.x & 31;
    int m = hl >> 3, q = hl & 7;    // member slot (4), feature octet (8)
    int s = eoff[e], t = eoff[e + 1];
    float8 acc = (float8)0.f;
    for (int j = s + m; j < t; j += 4) {
        int n = __ldg(&elist[j]);
        float8 v = cvt8(h8[(size_t)n * 8 + q]);
        acc += v;
    }
    acc += shflxor8(acc, 8);
    acc += shflxor8(acc, 16);
    if (m == 0) {
        float bv = binv[e];
        acc *= bv;
        efeat8[(size_t)e * 8 + q] = cvt16(acc);
    }
}

// 1 node per wave: 8 edge slots x 8 feature-octets; fused 64x64 GEMM + BN stats
__global__ void node_agg(const int* __restrict__ noff, const int* __restrict__ nlist,
                         const half8* __restrict__ efeat8, const float* __restrict__ dinv,
                         const float* __restrict__ W, const float* __restrict__ bvec,
                         __half* __restrict__ outr16, float* __restrict__ stats) {
    __shared__ float Ws[64 * 64];
    __shared__ float sA[4][64];
    __shared__ float sB[4][64];
    int tid = threadIdx.x;
    for (int i = tid; i < 64 * 64; i += 256) Ws[i] = W[i];
    __syncthreads();
    int wave = tid >> 6, lane = tid & 63;
    int slot = lane >> 3, q = lane & 7;   // 8 slots, 8 octets
    float sa = 0.f, sb = 0.f;
    for (int n = blockIdx.x * 4 + wave; n < N_NODES; n += gridDim.x * 4) {
        int s = noff[n], t = noff[n + 1];
        float8 acc = (float8)0.f;
        for (int j = s + slot; j < t; j += 8) {
            int e = __ldg(&nlist[j]);
            float8 v = cvt8(efeat8[(size_t)e * 8 + q]);
            acc += v;
        }
        acc += shflxor8(acc, 8);
        acc += shflxor8(acc, 16);
        acc += shflxor8(acc, 32);
        float dv = dinv[n];
        acc *= dv;
        // per-wave GEMM: out[lane] = b[lane] + sum_k row[k] * Ws[k][lane]
        // row[8*qq + r] lives in any lane with octet qq (broadcast from lane qq)
        float out = bvec[lane];
        #pragma unroll
        for (int qq = 0; qq < 8; ++qq) {
            float8 av;
            #pragma unroll
            for (int r = 0; r < 8; ++r) av[r] = __shfl(acc[r], qq);
            #pragma unroll
            for (int r = 0; r < 8; ++r)
                out = fmaf(av[r], Ws[(8 * qq + r) * 64 + lane], out);
        }
        if (t == s) out = 0.f;   // isolated node: reference gives exactly 0
        outr16[(size_t)n * 64 + lane] = __float2half_rn(out);
        sa += out; sb += out * out;
    }
    sA[wave][lane] = sa; sB[wave][lane] = sb;
    __syncthreads();
    if (tid < 64) {
        float a = sA[0][tid] + sA[1][tid] + sA[2][tid] + sA[3][tid];
        float b = sB[0][tid] + sB[1][tid] + sB[2][tid] + sB[3][tid];
        atomicAdd(&stats[tid], a);
        atomicAdd(&stats[64 + tid], b);
    }
}

// ---------------- BN + softplus ----------------

__global__ void bnfin_kernel(const float* __restrict__ stats, const float* __restrict__ gamma,
                             const float* __restrict__ beta, float* __restrict__ scsh) {
    int f = threadIdx.x;
    if (f >= 64) return;
    const float invN = 1.f / (float)N_NODES;
    float mean = stats[f] * invN;
    float var  = stats[64 + f] * invN - mean * mean;
    var = fmaxf(var, 0.f);
    float sc = gamma[f] * rsqrtf(var + BN_EPS);
    scsh[f]      = sc;
    scsh[64 + f] = beta[f] - mean * sc;
}

__global__ void apply_kernel(const half4* __restrict__ outr4, const float* __restrict__ scsh,
                             half4* __restrict__ h4) {
    int gid = blockIdx.x * 256 + threadIdx.x;   // over N_NODES*16 quads
    if (gid >= N_NODES * 16) return;
    int qq = gid & 15;
    half4 v = outr4[gid];
    float2 lo = __half22float2(v.a), hi = __half22float2(v.b);
    float4 sc = ((const float4*)scsh)[qq];
    float4 sh = ((const float4*)(scsh + 64))[qq];
    half4 r;
    r.a = __floats2half2_rn(softplus_f(fmaf(lo.x, sc.x, sh.x)),
                            softplus_f(fmaf(lo.y, sc.y, sh.y)));
    r.b = __floats2half2_rn(softplus_f(fmaf(hi.x, sc.z, sh.z)),
                            softplus_f(fmaf(hi.y, sc.w, sh.w)));
    h4[gid] = r;
}

// ---------------- pooling + head (batch is sorted -> segmented gather) ----------------

__global__ void graph_bounds(const int* __restrict__ batch, int* __restrict__ goff) {
    int g = blockIdx.x * 256 + threadIdx.x;
    if (g > N_GRAPHS) return;
    int lo = 0, hi = N_NODES;
    while (lo < hi) {
        int mid = (lo + hi) >> 1;
        if (batch[mid] < g) lo = mid + 1; else hi = mid;
    }
    goff[g] = lo;
}

__global__ void pool_head_kernel(const __half* __restrict__ h16, const int* __restrict__ goff,
                                 const float* __restrict__ fcW, const float* __restrict__ fcb,
                                 const float* __restrict__ fcoW, const float* __restrict__ fcob,
                                 float* __restrict__ out) {
    __shared__ float part[4][64];
    __shared__ float p[64];
    __shared__ float red[128];
    int g = blockIdx.x, tid = threadIdx.x;
    int s = goff[g], t = goff[g + 1];
    int f = tid & 63, r = tid >> 6;
    float acc = 0.f;
    for (int n = s + r; n < t; n += 4)
        acc += __half2float(h16[(size_t)n * 64 + f]);
    part[r][f] = acc;
    __syncthreads();
    if (tid < 64) {
        float v = part[0][tid] + part[1][tid] + part[2][tid] + part[3][tid];
        float c = fmaxf((float)(t - s), 1.f);
        p[tid] = softplus_f(v / c);
    }
    __syncthreads();
    if (tid < 128) {
        float a = fcb[tid];
        #pragma unroll
        for (int k = 0; k < 64; ++k)
            a = fmaf(p[k], fcW[k * H_DIM + tid], a);
        red[tid] = softplus_f(a) * fcoW[tid];
    }
    __syncthreads();
    for (int st = 64; st > 0; st >>= 1) {
        if (tid < st) red[tid] += red[tid + st];
        __syncthreads();
    }
    if (tid == 0) out[g] = red[0] + fcob[0];
}

// ---------------- launch ----------------

extern "C" void kernel_launch(void* const* d_in, const int* in_sizes, int n_in,
                              void* d_out, int out_size, void* d_ws, size_t ws_size,
                              hipStream_t stream) {
    const float* x      = (const float*)d_in[0];
    const float* W_emb  = (const float*)d_in[1];
    const float* b_emb  = (const float*)d_in[2];
    const float* conv_W = (const float*)d_in[3];
    const float* conv_b = (const float*)d_in[4];
    const float* bn_g   = (const float*)d_in[5];
    const float* bn_b   = (const float*)d_in[6];
    const float* fc_W   = (const float*)d_in[7];
    const float* fc_b   = (const float*)d_in[8];
    const float* fco_W  = (const float*)d_in[9];
    const float* fco_b  = (const float*)d_in[10];
    const int* node_idx = (const int*)d_in[11];
    const int* edge_idx = (const int*)d_in[12];
    const int* batch    = (const int*)d_in[13];
    float* out = (float*)d_out;

    // ---- workspace layout ----
    __half* h16    = (__half*)d_ws;                            // 6.4M halves
    __half* outr16 = h16    + (size_t)N_NODES * 64;            // 6.4M halves
    __half* efeat16= outr16 + (size_t)N_NODES * 64;            // 25.6M halves
    unsigned long long* staging = (unsigned long long*)(efeat16 + (size_t)N_EDGES * 64); // 1.6M u64
    float* binv    = (float*)(staging + N_INC);                // 400K
    float* dinv    = binv   + N_EDGES;                         // 100K
    float* stats   = dinv   + N_NODES;                         // 128
    float* scsh    = stats  + 128;                             // 128
    int*   goff    = (int*)(scsh + 128);                       // N_GRAPHS+1
    int*   eoff    = goff  + N_GRAPHS + 1;                     // 400K+1
    int*   noff    = eoff  + N_EDGES + 1;                      // 100K+1
    int*   gcountE = noff  + N_NODES + 1;                      // NBUCK
    int*   gcountN = gcountE + NBUCK;                          // NBUCK
    int*   bbaseE  = gcountN + NBUCK;                          // NBUCK+1
    int*   bbaseN  = bbaseE + NBUCK + 1;                       // NBUCK+1
    int*   gcurE   = bbaseN + NBUCK + 1;                       // NBUCK
    int*   gcurN   = gcurE + NBUCK;                            // NBUCK
    int*   elist   = gcurN + NBUCK;                            // 1.6M
    int*   nlist   = elist + N_INC;                            // 1.6M

    // ---- CSR build: two bucketed counting sorts ----
    hipMemsetAsync(gcountE, 0, 2 * NBUCK * sizeof(int), stream);
    bucket_hist<<<200, 256, 0, stream>>>(edge_idx, N_INC, 10, gcountE);
    bucket_scan<<<1, 512, 0, stream>>>(gcountE, bbaseE, gcurE);
    bucket_partition<<<(N_INC + PCHUNK - 1) / PCHUNK, 256, 0, stream>>>(
        edge_idx, node_idx, N_INC, 10, gcurE, staging);
    bucket_finalize<1024><<<NBUCK, 256, 0, stream>>>(staging, bbaseE, N_EDGES, binv, eoff, elist);
    bucket_hist<<<200, 256, 0, stream>>>(node_idx, N_INC, 8, gcountN);
    bucket_scan<<<1, 512, 0, stream>>>(gcountN, bbaseN, gcurN);
    bucket_partition<<<(N_INC + PCHUNK - 1) / PCHUNK, 256, 0, stream>>>(
        node_idx, edge_idx, N_INC, 8, gcurN, staging);
    bucket_finalize<256><<<NBUCK, 256, 0, stream>>>(staging, bbaseN, N_NODES, dinv, noff, nlist);

    // ---- graph boundaries (batch is sorted) ----
    graph_bounds<<<(N_GRAPHS + 1 + 255) / 256, 256, 0, stream>>>(batch, goff);

    // ---- embedding ----
    embed_kernel<<<(N_NODES + 3) / 4, 256, 0, stream>>>(x, W_emb, b_emb, h16);

    // ---- 3 hypergraph conv layers: agg = P h; out = agg@W + b; BN; softplus ----
    for (int l = 0; l < NUM_LAYERS; ++l) {
        const float* Wl = conv_W + (size_t)l * NODE_DIM * NODE_DIM;
        const float* bl = conv_b + (size_t)l * NODE_DIM;

        edge_agg<<<(N_EDGES + 7) / 8, 256, 0, stream>>>(eoff, elist, (const half8*)h16,
                                                        binv, (half8*)efeat16);
        hipMemsetAsync(stats, 0, 128 * sizeof(float), stream);
        node_agg<<<2048, 256, 0, stream>>>(noff, nlist, (const half8*)efeat16, dinv,
                                           Wl, bl, outr16, stats);
        bnfin_kernel<<<1, 64, 0, stream>>>(stats, bn_g + (size_t)l * 64, bn_b + (size_t)l * 64, scsh);
        apply_kernel<<<(N_NODES * 16 + 255) / 256, 256, 0, stream>>>((const half4*)outr16, scsh,
                                                                     (half4*)h16);
    }

    // ---- fused pooling + head ----
    pool_head_kernel<<<N_GRAPHS, 256, 0, stream>>>(h16, goff, fc_W, fc_b, fco_W, fco_b, out);
}